// Round 7
// baseline (745.838 us; speedup 1.0000x reference)
//
#include <hip/hip_runtime.h>
#include <hip/hip_bf16.h>
#include <math.h>

// ---------------------------------------------------------------------------
// LinearTransformerCausalDecoder on MI355X (gfx950)
// B=2, S=M=1024, D=512, H=8, HD=64, L=4, FF=2048
// d_in / d_out are FLOAT32. Weights pre-transposed to bf16 Wt[N][K] once.
// GEMM: m97-structure (BK=32 linear LDS, global_load_lds(16), dbuf).
// ---------------------------------------------------------------------------

typedef unsigned short u16;
typedef __bf16 bf16x8 __attribute__((ext_vector_type(8)));
typedef float f32x4v __attribute__((ext_vector_type(4)));

#define DEVI __device__ __forceinline__

DEVI float bf2f(u16 u) { return __uint_as_float(((unsigned)u) << 16); }
DEVI u16 f2bf(float f) {
  unsigned u = __float_as_uint(f);
  u += 0x7FFFu + ((u >> 16) & 1u);   // RNE
  return (u16)(u >> 16);
}

// async global->LDS, 16B per lane. lds base must be wave-uniform; HW adds lane*16.
DEVI void gload16(const void* g, void* lds) {
  __builtin_amdgcn_global_load_lds(
      (const __attribute__((address_space(1))) void*)g,
      (__attribute__((address_space(3))) void*)lds, 16, 0, 0);
}

// ---------------------------------------------------------------------------
// Batched weight transpose+convert: 8 weight sets (sa q,k,v,o / ca q,k,v,o),
// each [4][512][512] f32 [K][N] -> bf16 [N][K].  grid (8,8,32).
// ---------------------------------------------------------------------------
struct P8i { const float* p[8]; };
struct P8o { u16* p[8]; };

__global__ __launch_bounds__(256) void transpose_b8(P8i in, P8o out)
{
  __shared__ float tile[64 * 65];
  const int m = blockIdx.z;
  const int set = m >> 2, layer = m & 3;
  const float* src = in.p[set] + (size_t)layer * 512 * 512;
  u16* dst = out.p[set] + (size_t)layer * 512 * 512;
  const int n0 = blockIdx.x * 64, k0 = blockIdx.y * 64;
  const int t = threadIdx.x;
#pragma unroll
  for (int p = 0; p < 16; ++p) {
    const int e = t + p * 256;
    const int lk = e >> 6, ln = e & 63;
    tile[lk * 65 + ln] = src[(size_t)(k0 + lk) * 512 + n0 + ln];
  }
  __syncthreads();
#pragma unroll
  for (int p = 0; p < 16; ++p) {
    const int e = t + p * 256;
    const int ln = e >> 6, lk = e & 63;
    dst[(size_t)(n0 + ln) * 512 + k0 + lk] = f2bf(tile[lk * 65 + ln]);
  }
}

__global__ __launch_bounds__(256) void transpose_f2b(
    const float* __restrict__ in, u16* __restrict__ out, int K, int N)
{
  __shared__ float tile[64 * 65];
  const size_t mat = (size_t)blockIdx.z * K * N;
  const int n0 = blockIdx.x * 64, k0 = blockIdx.y * 64;
  const int t = threadIdx.x;
#pragma unroll
  for (int p = 0; p < 16; ++p) {
    const int e = t + p * 256;
    const int lk = e >> 6, ln = e & 63;
    tile[lk * 65 + ln] = in[mat + (size_t)(k0 + lk) * N + n0 + ln];
  }
  __syncthreads();
#pragma unroll
  for (int p = 0; p < 16; ++p) {
    const int e = t + p * 256;
    const int ln = e >> 6, lk = e & 63;
    out[mat + (size_t)(n0 + ln) * K + k0 + lk] = f2bf(tile[lk * 65 + ln]);
  }
}

// f32 -> (optional f32 copy) + bf16, 8 elems/thread, 1M elements (512 blocks)
__global__ __launch_bounds__(256) void cast_dual(
    const float* __restrict__ in, float* __restrict__ fout, u16* __restrict__ bout)
{
  const int i = blockIdx.x * 256 + threadIdx.x;
  const float4 a = ((const float4*)in)[i * 2];
  const float4 b = ((const float4*)in)[i * 2 + 1];
  if (fout) {
    ((float4*)fout)[i * 2] = a;
    ((float4*)fout)[i * 2 + 1] = b;
  }
  ((ushort4*)bout)[i * 2]     = make_ushort4(f2bf(a.x), f2bf(a.y), f2bf(a.z), f2bf(a.w));
  ((ushort4*)bout)[i * 2 + 1] = make_ushort4(f2bf(b.x), f2bf(b.y), f2bf(b.z), f2bf(b.w));
}

// ---------------------------------------------------------------------------
// Unified multi-segment GEMM (m97 structure): C_s = act_s(A_s @ Wt_s^T + b_s)
// A,Wt bf16. BK=32, linear LDS, global_load_lds(16B), double-buffered.
// 4 waves (2x2); wave tile (BM/2)x(BN/2); NM=BM/32, NN=BN/32 fragments.
// acts: 2 bits/segment (0 none, 1 phi=elu+1, 2 gelu exact). CDT: 0 f32, 1 bf16.
// ---------------------------------------------------------------------------
template<int BM, int BN, int CDT>
__global__ __launch_bounds__(256) void gemmT(
    const u16* __restrict__ A0, const u16* __restrict__ A1, const u16* __restrict__ A2,
    const u16* __restrict__ W0, const u16* __restrict__ W1, const u16* __restrict__ W2,
    const float* __restrict__ b0, const float* __restrict__ b1, const float* __restrict__ b2,
    void* __restrict__ C0, void* __restrict__ C1, void* __restrict__ C2,
    int acts, int N, int K, int lognyb)
{
  constexpr int NM = BM / 32, NN = BN / 32;
  __shared__ __align__(16) u16 As[2][BM * 32];
  __shared__ __align__(16) u16 Bs[2][BN * 32];
  const int tid = threadIdx.x;
  const int by = blockIdx.y;
  const int seg = by >> lognyb;
  const int ny = by & ((1 << lognyb) - 1);
  const u16* A = seg == 0 ? A0 : (seg == 1 ? A1 : A2);
  const u16* W = seg == 0 ? W0 : (seg == 1 ? W1 : W2);
  const float* bias = seg == 0 ? b0 : (seg == 1 ? b1 : b2);
  void* Cv = seg == 0 ? C0 : (seg == 1 ? C1 : C2);
  const int act = (acts >> (2 * seg)) & 3;

  const int bm0 = blockIdx.x * BM, bn0 = ny * BN;
  const int lane = tid & 63, wid = tid >> 6;
  const int wr = wid >> 1, wc = wid & 1;
  const int l15 = lane & 15, lg = lane >> 4;
  const int rl = lane >> 2, col8 = (lane & 3) * 8;   // staging: lane covers 16B

  auto stage = [&](int buf, int k0) {
#pragma unroll
    for (int p = 0; p < BM / 64; ++p) {
      const int ch = wid + 4 * p;                     // 1024B chunk
      gload16(&A[(size_t)(bm0 + ch * 16 + rl) * K + k0 + col8], &As[buf][ch * 512]);
    }
#pragma unroll
    for (int p = 0; p < BN / 64; ++p) {
      const int ch = wid + 4 * p;
      gload16(&W[(size_t)(bn0 + ch * 16 + rl) * K + k0 + col8], &Bs[buf][ch * 512]);
    }
  };

  stage(0, 0);
  __syncthreads();
  f32x4v acc[NM][NN] = {};
  int cur = 0;
  for (int k0 = 0; k0 < K; k0 += 32) {
    if (k0 + 32 < K) stage(cur ^ 1, k0 + 32);
    bf16x8 af[NM], bw[NN];
#pragma unroll
    for (int mm = 0; mm < NM; ++mm)
      af[mm] = *(const bf16x8*)&As[cur][(wr * (BM / 2) + mm * 16 + l15) * 32 + lg * 8];
#pragma unroll
    for (int nn = 0; nn < NN; ++nn)
      bw[nn] = *(const bf16x8*)&Bs[cur][(wc * (BN / 2) + nn * 16 + l15) * 32 + lg * 8];
#pragma unroll
    for (int mm = 0; mm < NM; ++mm)
#pragma unroll
      for (int nn = 0; nn < NN; ++nn)
        acc[mm][nn] = __builtin_amdgcn_mfma_f32_16x16x32_bf16(af[mm], bw[nn], acc[mm][nn], 0, 0, 0);
    __syncthreads();
    cur ^= 1;
  }
#pragma unroll
  for (int nn = 0; nn < NN; ++nn) {
    const int col = bn0 + wc * (BN / 2) + nn * 16 + l15;
    const float bv = bias[col];
#pragma unroll
    for (int mm = 0; mm < NM; ++mm) {
#pragma unroll
      for (int r = 0; r < 4; ++r) {
        const int row = bm0 + wr * (BM / 2) + mm * 16 + lg * 4 + r;
        float v = acc[mm][nn][r] + bv;
        if (act == 1) v = v > 0.f ? v + 1.f : __expf(v);
        else if (act == 2) v = 0.5f * v * (1.f + erff(v * 0.70710678f));
        if (CDT == 0) ((float*)Cv)[(size_t)row * N + col] = v;
        else          ((u16*)Cv)[(size_t)row * N + col] = f2bf(v);
      }
    }
  }
}

// ---------------------------------------------------------------------------
// Chunk sums (MFMA): per (c,bh): KVt[m][d] = sum_s V[s][m]*K[s][d] (f32 out),
// z[d] = sum_s K[s][d].  Inputs bf16.
// ---------------------------------------------------------------------------
__global__ __launch_bounds__(256) void lin_chunk_mfma(
    const u16* __restrict__ kbuf, const u16* __restrict__ vbuf,
    float* __restrict__ KVc, float* __restrict__ zc)
{
  constexpr int LDT = 72;
  __shared__ __align__(16) u16 Kt[64 * LDT];   // Kt[d][s]
  __shared__ __align__(16) u16 Vt[64 * LDT];   // Vt[m][s]
  const int c = blockIdx.x, bh = blockIdx.y;
  const int b = bh >> 3, h = bh & 7;
  const int t = threadIdx.x;
  const size_t rowbase = (size_t)(b * 1024 + c * 64);
  const int sp = t >> 4, colq = (t & 15) * 4;
#pragma unroll
  for (int pp = 0; pp < 2; ++pp) {
    const int s0 = pp * 32 + 2 * sp;
    const ushort4 ka = *(const ushort4*)&kbuf[(rowbase + s0) * 512 + h * 64 + colq];
    const ushort4 kb_ = *(const ushort4*)&kbuf[(rowbase + s0 + 1) * 512 + h * 64 + colq];
    const ushort4 va = *(const ushort4*)&vbuf[(rowbase + s0) * 512 + h * 64 + colq];
    const ushort4 vb_ = *(const ushort4*)&vbuf[(rowbase + s0 + 1) * 512 + h * 64 + colq];
    *(unsigned*)&Kt[(colq + 0) * LDT + s0] = (unsigned)ka.x | ((unsigned)kb_.x << 16);
    *(unsigned*)&Kt[(colq + 1) * LDT + s0] = (unsigned)ka.y | ((unsigned)kb_.y << 16);
    *(unsigned*)&Kt[(colq + 2) * LDT + s0] = (unsigned)ka.z | ((unsigned)kb_.z << 16);
    *(unsigned*)&Kt[(colq + 3) * LDT + s0] = (unsigned)ka.w | ((unsigned)kb_.w << 16);
    *(unsigned*)&Vt[(colq + 0) * LDT + s0] = (unsigned)va.x | ((unsigned)vb_.x << 16);
    *(unsigned*)&Vt[(colq + 1) * LDT + s0] = (unsigned)va.y | ((unsigned)vb_.y << 16);
    *(unsigned*)&Vt[(colq + 2) * LDT + s0] = (unsigned)va.z | ((unsigned)vb_.z << 16);
    *(unsigned*)&Vt[(colq + 3) * LDT + s0] = (unsigned)va.w | ((unsigned)vb_.w << 16);
  }
  __syncthreads();
  {
    const int zd = t >> 2, zg = t & 3;
    float zp = 0.f;
#pragma unroll
    for (int ss = 0; ss < 16; ++ss) zp += bf2f(Kt[zd * LDT + zg * 16 + ss]);
    zp += __shfl_xor(zp, 1, 64);
    zp += __shfl_xor(zp, 2, 64);
    if (zg == 0) zc[(size_t)(bh * 16 + c) * 64 + zd] = zp;
  }
  const int lane = t & 63, wid = t >> 6;
  const int wr = wid >> 1, wc = wid & 1;
  const int l15 = lane & 15, lg = lane >> 4;
  bf16x8 av[2][2], bk[2][2];
#pragma unroll
  for (int kk = 0; kk < 2; ++kk) {
#pragma unroll
    for (int mm = 0; mm < 2; ++mm)
      av[kk][mm] = *(const bf16x8*)&Vt[(wr * 32 + mm * 16 + l15) * LDT + kk * 32 + lg * 8];
#pragma unroll
    for (int nn = 0; nn < 2; ++nn)
      bk[kk][nn] = *(const bf16x8*)&Kt[(wc * 32 + nn * 16 + l15) * LDT + kk * 32 + lg * 8];
  }
  f32x4v acc[2][2] = {};
#pragma unroll
  for (int kk = 0; kk < 2; ++kk)
#pragma unroll
    for (int mm = 0; mm < 2; ++mm)
#pragma unroll
      for (int nn = 0; nn < 2; ++nn)
        acc[mm][nn] = __builtin_amdgcn_mfma_f32_16x16x32_bf16(av[kk][mm], bk[kk][nn], acc[mm][nn], 0, 0, 0);
  float* kvout = KVc + (size_t)(bh * 16 + c) * 4096;
#pragma unroll
  for (int mm = 0; mm < 2; ++mm)
#pragma unroll
    for (int r = 0; r < 4; ++r) {
      const int row = wr * 32 + mm * 16 + lg * 4 + r;
#pragma unroll
      for (int nn = 0; nn < 2; ++nn) {
        const int col = wc * 32 + nn * 16 + l15;
        kvout[row * 64 + col] = acc[mm][nn][r];
      }
    }
}

// ---------------------------------------------------------------------------
// SA apply (MFMA): prefix-sums KVc/zc chunks [0,c) in-kernel, then
// S=Q@K^T masked; O = S@V + Q@KVprefix; den = rowsum(S)+Q.zp.  bf16 in/out.
// ---------------------------------------------------------------------------
__global__ __launch_bounds__(256) void sa_apply_mfma(
    const u16* __restrict__ qbuf, const u16* __restrict__ kbuf,
    const u16* __restrict__ vbuf, const float* __restrict__ KVc,
    const float* __restrict__ zc, u16* __restrict__ out)
{
  constexpr int LDT = 72;
  __shared__ __align__(16) u16 Qs[64 * LDT];   // [i][d]
  __shared__ __align__(16) u16 Ks[64 * LDT];   // [j][d]
  __shared__ __align__(16) u16 Vt[64 * LDT];   // [m][j]
  __shared__ __align__(16) u16 Ps[64 * LDT];   // [i][j]
  __shared__ __align__(16) u16 KVs[64 * LDT];  // [m][d] (prefix)
  __shared__ float zp[64];
  __shared__ float den1[2][64];
  __shared__ float den2[64];
  const int c = blockIdx.x, bh = blockIdx.y;
  const int b = bh >> 3, h = bh & 7;
  const int t = threadIdx.x;
  const size_t rowbase = (size_t)(b * 1024 + c * 64);
  {
    const int srow = t >> 2, scg = (t & 3) * 16;
    *(uint4*)&Qs[srow * LDT + scg]     = *(const uint4*)&qbuf[(rowbase + srow) * 512 + h * 64 + scg];
    *(uint4*)&Qs[srow * LDT + scg + 8] = *(const uint4*)&qbuf[(rowbase + srow) * 512 + h * 64 + scg + 8];
    *(uint4*)&Ks[srow * LDT + scg]     = *(const uint4*)&kbuf[(rowbase + srow) * 512 + h * 64 + scg];
    *(uint4*)&Ks[srow * LDT + scg + 8] = *(const uint4*)&kbuf[(rowbase + srow) * 512 + h * 64 + scg + 8];
    // KV prefix = sum of chunks [0, c) in ascending order (matches old scan)
    const float* kvbase = KVc + (size_t)(bh * 16) * 4096 + srow * 64 + scg;
    float4 s0 = make_float4(0, 0, 0, 0), s1 = s0, s2 = s0, s3 = s0;
    for (int cc = 0; cc < c; ++cc) {
      const float* p = kvbase + (size_t)cc * 4096;
      const float4 a0 = *(const float4*)&p[0];
      const float4 a1 = *(const float4*)&p[4];
      const float4 a2 = *(const float4*)&p[8];
      const float4 a3 = *(const float4*)&p[12];
      s0.x += a0.x; s0.y += a0.y; s0.z += a0.z; s0.w += a0.w;
      s1.x += a1.x; s1.y += a1.y; s1.z += a1.z; s1.w += a1.w;
      s2.x += a2.x; s2.y += a2.y; s2.z += a2.z; s2.w += a2.w;
      s3.x += a3.x; s3.y += a3.y; s3.z += a3.z; s3.w += a3.w;
    }
    *(ushort4*)&KVs[srow * LDT + scg + 0]  = make_ushort4(f2bf(s0.x), f2bf(s0.y), f2bf(s0.z), f2bf(s0.w));
    *(ushort4*)&KVs[srow * LDT + scg + 4]  = make_ushort4(f2bf(s1.x), f2bf(s1.y), f2bf(s1.z), f2bf(s1.w));
    *(ushort4*)&KVs[srow * LDT + scg + 8]  = make_ushort4(f2bf(s2.x), f2bf(s2.y), f2bf(s2.z), f2bf(s2.w));
    *(ushort4*)&KVs[srow * LDT + scg + 12] = make_ushort4(f2bf(s3.x), f2bf(s3.y), f2bf(s3.z), f2bf(s3.w));
  }
  {
    const int sp = t >> 4, colq = (t & 15) * 4;
#pragma unroll
    for (int pp = 0; pp < 2; ++pp) {
      const int s0 = pp * 32 + 2 * sp;
      const ushort4 va = *(const ushort4*)&vbuf[(rowbase + s0) * 512 + h * 64 + colq];
      const ushort4 vb_ = *(const ushort4*)&vbuf[(rowbase + s0 + 1) * 512 + h * 64 + colq];
      *(unsigned*)&Vt[(colq + 0) * LDT + s0] = (unsigned)va.x | ((unsigned)vb_.x << 16);
      *(unsigned*)&Vt[(colq + 1) * LDT + s0] = (unsigned)va.y | ((unsigned)vb_.y << 16);
      *(unsigned*)&Vt[(colq + 2) * LDT + s0] = (unsigned)va.z | ((unsigned)vb_.z << 16);
      *(unsigned*)&Vt[(colq + 3) * LDT + s0] = (unsigned)va.w | ((unsigned)vb_.w << 16);
    }
  }
  if (t < 64) {
    float z = 0.f;
    for (int cc = 0; cc < c; ++cc) z += zc[(size_t)(bh * 16 + cc) * 64 + t];
    zp[t] = z;
  }
  __syncthreads();
  {
    const int di = t >> 2, dg = t & 3;
    float p2 = 0.f;
#pragma unroll
    for (int dd = 0; dd < 16; ++dd)
      p2 += bf2f(Qs[di * LDT + dg * 16 + dd]) * zp[dg * 16 + dd];
    p2 += __shfl_xor(p2, 1, 64);
    p2 += __shfl_xor(p2, 2, 64);
    if (dg == 0) den2[di] = p2;
  }
  const int lane = t & 63, wid = t >> 6;
  const int wr = wid >> 1, wc = wid & 1;
  const int l15 = lane & 15, lg = lane >> 4;
  bf16x8 af_q[2][2], bx[2][2];
#pragma unroll
  for (int kk = 0; kk < 2; ++kk) {
#pragma unroll
    for (int mm = 0; mm < 2; ++mm)
      af_q[kk][mm] = *(const bf16x8*)&Qs[(wr * 32 + mm * 16 + l15) * LDT + kk * 32 + lg * 8];
#pragma unroll
    for (int nn = 0; nn < 2; ++nn)
      bx[kk][nn] = *(const bf16x8*)&Ks[(wc * 32 + nn * 16 + l15) * LDT + kk * 32 + lg * 8];
  }
  f32x4v s_acc[2][2] = {};
#pragma unroll
  for (int kk = 0; kk < 2; ++kk)
#pragma unroll
    for (int mm = 0; mm < 2; ++mm)
#pragma unroll
      for (int nn = 0; nn < 2; ++nn)
        s_acc[mm][nn] = __builtin_amdgcn_mfma_f32_16x16x32_bf16(af_q[kk][mm], bx[kk][nn], s_acc[mm][nn], 0, 0, 0);
#pragma unroll
  for (int mm = 0; mm < 2; ++mm)
#pragma unroll
    for (int r = 0; r < 4; ++r) {
      const int row = wr * 32 + mm * 16 + lg * 4 + r;
      float dsum = 0.f;
#pragma unroll
      for (int nn = 0; nn < 2; ++nn) {
        const int col = wc * 32 + nn * 16 + l15;
        const float val = (col <= row) ? s_acc[mm][nn][r] : 0.f;
        Ps[row * LDT + col] = f2bf(val);
        dsum += val;
      }
      dsum += __shfl_xor(dsum, 1, 64);
      dsum += __shfl_xor(dsum, 2, 64);
      dsum += __shfl_xor(dsum, 4, 64);
      dsum += __shfl_xor(dsum, 8, 64);
      if (l15 == 0) den1[wc][row] = dsum;
    }
  __syncthreads();
  bf16x8 ap[2][2];
#pragma unroll
  for (int kk = 0; kk < 2; ++kk) {
#pragma unroll
    for (int mm = 0; mm < 2; ++mm)
      ap[kk][mm] = *(const bf16x8*)&Ps[(wr * 32 + mm * 16 + l15) * LDT + kk * 32 + lg * 8];
#pragma unroll
    for (int nn = 0; nn < 2; ++nn)
      bx[kk][nn] = *(const bf16x8*)&Vt[(wc * 32 + nn * 16 + l15) * LDT + kk * 32 + lg * 8];
  }
  f32x4v o_acc[2][2] = {};
#pragma unroll
  for (int kk = 0; kk < 2; ++kk)
#pragma unroll
    for (int mm = 0; mm < 2; ++mm)
#pragma unroll
      for (int nn = 0; nn < 2; ++nn)
        o_acc[mm][nn] = __builtin_amdgcn_mfma_f32_16x16x32_bf16(ap[kk][mm], bx[kk][nn], o_acc[mm][nn], 0, 0, 0);
#pragma unroll
  for (int kk = 0; kk < 2; ++kk)
#pragma unroll
    for (int nn = 0; nn < 2; ++nn)
      bx[kk][nn] = *(const bf16x8*)&KVs[(wc * 32 + nn * 16 + l15) * LDT + kk * 32 + lg * 8];
#pragma unroll
  for (int kk = 0; kk < 2; ++kk)
#pragma unroll
    for (int mm = 0; mm < 2; ++mm)
#pragma unroll
      for (int nn = 0; nn < 2; ++nn)
        o_acc[mm][nn] = __builtin_amdgcn_mfma_f32_16x16x32_bf16(af_q[kk][mm], bx[kk][nn], o_acc[mm][nn], 0, 0, 0);
#pragma unroll
  for (int mm = 0; mm < 2; ++mm)
#pragma unroll
    for (int r = 0; r < 4; ++r) {
      const int row = wr * 32 + mm * 16 + lg * 4 + r;
      const float rden = 1.f / (den1[0][row] + den1[1][row] + den2[row] + 1e-6f);
#pragma unroll
      for (int nn = 0; nn < 2; ++nn) {
        const int col = wc * 32 + nn * 16 + l15;
        out[(rowbase + row) * 512 + h * 64 + col] = f2bf(o_acc[mm][nn][r] * rden);
      }
    }
}

// ---------------------------------------------------------------------------
// CA apply (MFMA): sums all 16 chunk partials in-kernel; O = Q@KVtot / den.
// ---------------------------------------------------------------------------
__global__ __launch_bounds__(256) void ca_apply_mfma(
    const u16* __restrict__ qbuf, const float* __restrict__ KVc,
    const float* __restrict__ zc, u16* __restrict__ out)
{
  constexpr int LDT = 72;
  __shared__ __align__(16) u16 Qs[64 * LDT];
  __shared__ __align__(16) u16 KVs[64 * LDT];
  __shared__ float zt[64];
  __shared__ float den2[64];
  const int c = blockIdx.x, bh = blockIdx.y;
  const int b = bh >> 3, h = bh & 7;
  const int t = threadIdx.x;
  const size_t rowbase = (size_t)(b * 1024 + c * 64);
  {
    const int srow = t >> 2, scg = (t & 3) * 16;
    *(uint4*)&Qs[srow * LDT + scg]     = *(const uint4*)&qbuf[(rowbase + srow) * 512 + h * 64 + scg];
    *(uint4*)&Qs[srow * LDT + scg + 8] = *(const uint4*)&qbuf[(rowbase + srow) * 512 + h * 64 + scg + 8];
    const float* kvbase = KVc + (size_t)(bh * 16) * 4096 + srow * 64 + scg;
    float4 s0 = make_float4(0, 0, 0, 0), s1 = s0, s2 = s0, s3 = s0;
    for (int cc = 0; cc < 16; ++cc) {
      const float* p = kvbase + (size_t)cc * 4096;
      const float4 a0 = *(const float4*)&p[0];
      const float4 a1 = *(const float4*)&p[4];
      const float4 a2 = *(const float4*)&p[8];
      const float4 a3 = *(const float4*)&p[12];
      s0.x += a0.x; s0.y += a0.y; s0.z += a0.z; s0.w += a0.w;
      s1.x += a1.x; s1.y += a1.y; s1.z += a1.z; s1.w += a1.w;
      s2.x += a2.x; s2.y += a2.y; s2.z += a2.z; s2.w += a2.w;
      s3.x += a3.x; s3.y += a3.y; s3.z += a3.z; s3.w += a3.w;
    }
    *(ushort4*)&KVs[srow * LDT + scg + 0]  = make_ushort4(f2bf(s0.x), f2bf(s0.y), f2bf(s0.z), f2bf(s0.w));
    *(ushort4*)&KVs[srow * LDT + scg + 4]  = make_ushort4(f2bf(s1.x), f2bf(s1.y), f2bf(s1.z), f2bf(s1.w));
    *(ushort4*)&KVs[srow * LDT + scg + 8]  = make_ushort4(f2bf(s2.x), f2bf(s2.y), f2bf(s2.z), f2bf(s2.w));
    *(ushort4*)&KVs[srow * LDT + scg + 12] = make_ushort4(f2bf(s3.x), f2bf(s3.y), f2bf(s3.z), f2bf(s3.w));
  }
  if (t < 64) {
    float z = 0.f;
    for (int cc = 0; cc < 16; ++cc) z += zc[(size_t)(bh * 16 + cc) * 64 + t];
    zt[t] = z;
  }
  __syncthreads();
  {
    const int di = t >> 2, dg = t & 3;
    float p2 = 0.f;
#pragma unroll
    for (int dd = 0; dd < 16; ++dd)
      p2 += bf2f(Qs[di * LDT + dg * 16 + dd]) * zt[dg * 16 + dd];
    p2 += __shfl_xor(p2, 1, 64);
    p2 += __shfl_xor(p2, 2, 64);
    if (dg == 0) den2[di] = p2;
  }
  const int lane = t & 63, wid = t >> 6;
  const int wr = wid >> 1, wc = wid & 1;
  const int l15 = lane & 15, lg = lane >> 4;
  bf16x8 aq[2][2], bkv[2][2];
#pragma unroll
  for (int kk = 0; kk < 2; ++kk) {
#pragma unroll
    for (int mm = 0; mm < 2; ++mm)
      aq[kk][mm] = *(const bf16x8*)&Qs[(wr * 32 + mm * 16 + l15) * LDT + kk * 32 + lg * 8];
#pragma unroll
    for (int nn = 0; nn < 2; ++nn)
      bkv[kk][nn] = *(const bf16x8*)&KVs[(wc * 32 + nn * 16 + l15) * LDT + kk * 32 + lg * 8];
  }
  f32x4v o_acc[2][2] = {};
#pragma unroll
  for (int kk = 0; kk < 2; ++kk)
#pragma unroll
    for (int mm = 0; mm < 2; ++mm)
#pragma unroll
      for (int nn = 0; nn < 2; ++nn)
        o_acc[mm][nn] = __builtin_amdgcn_mfma_f32_16x16x32_bf16(aq[kk][mm], bkv[kk][nn], o_acc[mm][nn], 0, 0, 0);
  __syncthreads();
#pragma unroll
  for (int mm = 0; mm < 2; ++mm)
#pragma unroll
    for (int r = 0; r < 4; ++r) {
      const int row = wr * 32 + mm * 16 + lg * 4 + r;
      const float rden = 1.f / (den2[row] + 1e-6f);
#pragma unroll
      for (int nn = 0; nn < 2; ++nn) {
        const int col = wc * 32 + nn * 16 + l15;
        out[(rowbase + row) * 512 + h * 64 + col] = f2bf(o_acc[mm][nn][r] * rden);
      }
    }
}

// ---------------------------------------------------------------------------
// LayerNorm: x = LN(x + a) in place (f32) + bf16 mirror xb.
// ---------------------------------------------------------------------------
__global__ __launch_bounds__(256) void ln_residual(
    float* __restrict__ x, const float* __restrict__ a,
    const float* __restrict__ g, const float* __restrict__ bt,
    u16* __restrict__ xb)
{
  const int t = threadIdx.x, lane = t & 63, w = t >> 6;
  const int row = blockIdx.x * 4 + w;
  float* xr = x + (size_t)row * 512;
  const float* ar = a + (size_t)row * 512;
  float4 x0 = *(const float4*)&xr[lane * 8];
  float4 x1 = *(const float4*)&xr[lane * 8 + 4];
  float4 a0 = *(const float4*)&ar[lane * 8];
  float4 a1 = *(const float4*)&ar[lane * 8 + 4];
  float v[8];
  v[0] = x0.x + a0.x; v[1] = x0.y + a0.y; v[2] = x0.z + a0.z; v[3] = x0.w + a0.w;
  v[4] = x1.x + a1.x; v[5] = x1.y + a1.y; v[6] = x1.z + a1.z; v[7] = x1.w + a1.w;
  float s = 0.f, sq = 0.f;
#pragma unroll
  for (int i = 0; i < 8; ++i) { s += v[i]; sq += v[i] * v[i]; }
#pragma unroll
  for (int off = 32; off > 0; off >>= 1) {
    s += __shfl_xor(s, off, 64);
    sq += __shfl_xor(sq, off, 64);
  }
  const float mean = s * (1.f / 512.f);
  const float var = sq * (1.f / 512.f) - mean * mean;
  const float rstd = rsqrtf(var + 1e-5f);
  float o[8];
#pragma unroll
  for (int i = 0; i < 8; ++i) {
    const int col = lane * 8 + i;
    o[i] = (v[i] - mean) * rstd * g[col] + bt[col];
  }
  *(float4*)&xr[lane * 8]     = make_float4(o[0], o[1], o[2], o[3]);
  *(float4*)&xr[lane * 8 + 4] = make_float4(o[4], o[5], o[6], o[7]);
  *(ushort4*)&xb[(size_t)row * 512 + lane * 8]     = make_ushort4(f2bf(o[0]), f2bf(o[1]), f2bf(o[2]), f2bf(o[3]));
  *(ushort4*)&xb[(size_t)row * 512 + lane * 8 + 4] = make_ushort4(f2bf(o[4]), f2bf(o[5]), f2bf(o[6]), f2bf(o[7]));
}

__global__ __launch_bounds__(256) void ln_final(
    const float* __restrict__ x, const float* __restrict__ g,
    const float* __restrict__ bt, float* __restrict__ out)
{
  const int t = threadIdx.x, lane = t & 63, w = t >> 6;
  const int row = blockIdx.x * 4 + w;
  const float* xr = x + (size_t)row * 512;
  float4 x0 = *(const float4*)&xr[lane * 8];
  float4 x1 = *(const float4*)&xr[lane * 8 + 4];
  float v[8] = { x0.x, x0.y, x0.z, x0.w, x1.x, x1.y, x1.z, x1.w };
  float s = 0.f, sq = 0.f;
#pragma unroll
  for (int i = 0; i < 8; ++i) { s += v[i]; sq += v[i] * v[i]; }
#pragma unroll
  for (int off = 32; off > 0; off >>= 1) {
    s += __shfl_xor(s, off, 64);
    sq += __shfl_xor(sq, off, 64);
  }
  const float mean = s * (1.f / 512.f);
  const float var = sq * (1.f / 512.f) - mean * mean;
  const float rstd = rsqrtf(var + 1e-5f);
  float o[8];
#pragma unroll
  for (int i = 0; i < 8; ++i) {
    const int col = lane * 8 + i;
    o[i] = (v[i] - mean) * rstd * g[col] + bt[col];
  }
  *(float4*)&out[(size_t)row * 512 + lane * 8]     = make_float4(o[0], o[1], o[2], o[3]);
  *(float4*)&out[(size_t)row * 512 + lane * 8 + 4] = make_float4(o[4], o[5], o[6], o[7]);
}

// ---------------------------------------------------------------------------
extern "C" void kernel_launch(void* const* d_in, const int* in_sizes, int n_in,
                              void* d_out, int out_size, void* d_ws, size_t ws_size,
                              hipStream_t stream)
{
  (void)in_sizes; (void)n_in; (void)out_size; (void)ws_size;
  constexpr int Dm = 512, Lc = 4, FFc = 2048;

  const float* memory = (const float*)d_in[0];
  const float* target = (const float*)d_in[1];
  const float *saW[4], *sab[4], *caW[4], *cab[4];
  for (int j = 0; j < 4; ++j) {
    saW[j] = (const float*)d_in[2 + 2 * j];
    sab[j] = (const float*)d_in[3 + 2 * j];
    caW[j] = (const float*)d_in[10 + 2 * j];
    cab[j] = (const float*)d_in[11 + 2 * j];
  }
  const float* ffW1 = (const float*)d_in[18];
  const float* ffb1 = (const float*)d_in[19];
  const float* ffW2 = (const float*)d_in[20];
  const float* ffb2 = (const float*)d_in[21];
  const float* lng[4] = { (const float*)d_in[22], (const float*)d_in[24],
                          (const float*)d_in[26], (const float*)d_in[28] };
  const float* lnb[4] = { (const float*)d_in[23], (const float*)d_in[25],
                          (const float*)d_in[27], (const float*)d_in[29] };

  size_t off = 0;
  auto alloc = [&](size_t bytes) -> void* {
    void* p = (char*)d_ws + off;
    off += (bytes + 255) & ~(size_t)255;
    return p;
  };
  u16* WtS[4]; u16* WtC[4];
  for (int j = 0; j < 4; ++j) WtS[j] = (u16*)alloc((size_t)Lc * Dm * Dm * 2);
  for (int j = 0; j < 4; ++j) WtC[j] = (u16*)alloc((size_t)Lc * Dm * Dm * 2);
  u16* WtF1 = (u16*)alloc((size_t)Lc * Dm * FFc * 2);
  u16* WtF2 = (u16*)alloc((size_t)Lc * FFc * Dm * 2);
  float* x    = (float*)alloc((size_t)2048 * 512 * 4);
  u16*   xb   = (u16*)alloc((size_t)2048 * 512 * 2);
  u16*   memb = (u16*)alloc((size_t)2048 * 512 * 2);
  u16*   qh   = (u16*)alloc((size_t)2048 * 512 * 2);
  u16*   kh   = (u16*)alloc((size_t)2048 * 512 * 2);
  u16*   vh   = (u16*)alloc((size_t)2048 * 512 * 2);
  float* resid= (float*)alloc((size_t)2048 * 512 * 4);
  u16*   attn = (u16*)alloc((size_t)2048 * 512 * 2);
  u16*   ffh  = (u16*)alloc((size_t)2048 * 2048 * 2);
  float* KVc  = (float*)alloc((size_t)16 * 16 * 4096 * 4);
  float* zcb  = (float*)alloc((size_t)16 * 16 * 64 * 4);

  {
    P8i pin; P8o pout;
    for (int j = 0; j < 4; ++j) { pin.p[j] = saW[j]; pout.p[j] = WtS[j]; }
    for (int j = 0; j < 4; ++j) { pin.p[4 + j] = caW[j]; pout.p[4 + j] = WtC[j]; }
    transpose_b8<<<dim3(8, 8, 32), 256, 0, stream>>>(pin, pout);
  }
  transpose_f2b<<<dim3(32, 8, 4), 256, 0, stream>>>(ffW1, WtF1, Dm, FFc);
  transpose_f2b<<<dim3(8, 32, 4), 256, 0, stream>>>(ffW2, WtF2, FFc, Dm);

  cast_dual<<<512, 256, 0, stream>>>(target, x, xb);
  cast_dual<<<512, 256, 0, stream>>>(memory, nullptr, memb);

  for (int i = 0; i < Lc; ++i) {
    const size_t wo  = (size_t)i * Dm * Dm;
    const size_t wo1 = (size_t)i * Dm * FFc;
    const size_t wo2 = (size_t)i * FFc * Dm;
    // ---- causal linear self-attention ----
    gemmT<128, 128, 1><<<dim3(16, 12), 256, 0, stream>>>(
        xb, xb, xb, WtS[0] + wo, WtS[1] + wo, WtS[2] + wo,
        sab[0] + i * Dm, sab[1] + i * Dm, sab[2] + i * Dm,
        qh, kh, vh, 0x05, 512, 512, 2);
    lin_chunk_mfma<<<dim3(16, 16), 256, 0, stream>>>(kh, vh, KVc, zcb);
    sa_apply_mfma<<<dim3(16, 16), 256, 0, stream>>>(qh, kh, vh, KVc, zcb, attn);
    gemmT<64, 64, 0><<<dim3(32, 8), 256, 0, stream>>>(
        attn, attn, attn, WtS[3] + wo, WtS[3] + wo, WtS[3] + wo,
        sab[3] + i * Dm, sab[3] + i * Dm, sab[3] + i * Dm,
        resid, resid, resid, 0, 512, 512, 3);
    ln_residual<<<512, 256, 0, stream>>>(x, resid, lng[0] + i * Dm, lnb[0] + i * Dm, xb);
    // ---- linear cross-attention ----
    gemmT<128, 128, 1><<<dim3(16, 12), 256, 0, stream>>>(
        xb, memb, memb, WtC[0] + wo, WtC[1] + wo, WtC[2] + wo,
        cab[0] + i * Dm, cab[1] + i * Dm, cab[2] + i * Dm,
        qh, kh, vh, 0x05, 512, 512, 2);
    lin_chunk_mfma<<<dim3(16, 16), 256, 0, stream>>>(kh, vh, KVc, zcb);
    ca_apply_mfma<<<dim3(16, 16), 256, 0, stream>>>(qh, KVc, zcb, attn);
    gemmT<64, 64, 0><<<dim3(32, 8), 256, 0, stream>>>(
        attn, attn, attn, WtC[3] + wo, WtC[3] + wo, WtC[3] + wo,
        cab[3] + i * Dm, cab[3] + i * Dm, cab[3] + i * Dm,
        resid, resid, resid, 0, 512, 512, 3);
    ln_residual<<<512, 256, 0, stream>>>(x, resid, lng[1] + i * Dm, lnb[1] + i * Dm, xb);
    // ---- FFN ----
    gemmT<128, 128, 1><<<dim3(16, 16), 256, 0, stream>>>(
        xb, xb, xb, WtF1 + wo1, WtF1 + wo1, WtF1 + wo1,
        ffb1 + i * FFc, ffb1 + i * FFc, ffb1 + i * FFc,
        ffh, ffh, ffh, 2, 2048, 512, 4);
    gemmT<64, 64, 0><<<dim3(32, 8), 256, 0, stream>>>(
        ffh, ffh, ffh, WtF2 + wo2, WtF2 + wo2, WtF2 + wo2,
        ffb2 + i * Dm, ffb2 + i * Dm, ffb2 + i * Dm,
        resid, resid, resid, 0, 512, 2048, 3);
    ln_residual<<<512, 256, 0, stream>>>(x, resid, lng[2] + i * Dm, lnb[2] + i * Dm, xb);
  }
  ln_final<<<512, 256, 0, stream>>>(x, lng[3], lnb[3], (float*)d_out);
}

// Round 8
// 596.639 us; speedup vs baseline: 1.2501x; 1.2501x over previous
//
#include <hip/hip_runtime.h>
#include <hip/hip_bf16.h>
#include <math.h>

// ---------------------------------------------------------------------------
// LinearTransformerCausalDecoder on MI355X (gfx950)
// B=2, S=M=1024, D=512, H=8, HD=64, L=4, FF=2048
// d_in / d_out FLOAT32. Weights pre-transposed to bf16 Wt[N][K] once.
// GEMM: round-6 structure (BK=64, LDT=72, reg-staged dbuf) + z-stride batching.
// CA K/V + CA chunk sums hoisted across layers; FFN2 split-K=4.
// ---------------------------------------------------------------------------

typedef unsigned short u16;
typedef __bf16 bf16x8 __attribute__((ext_vector_type(8)));
typedef float f32x4v __attribute__((ext_vector_type(4)));
typedef long long i64;

#define DEVI __device__ __forceinline__

DEVI float bf2f(u16 u) { return __uint_as_float(((unsigned)u) << 16); }
DEVI u16 f2bf(float f) {
  unsigned u = __float_as_uint(f);
  u += 0x7FFFu + ((u >> 16) & 1u);   // RNE
  return (u16)(u >> 16);
}

// ---------------------------------------------------------------------------
// Batched weight transpose+convert: 8 sets (sa q,k,v,o / ca q,k,v,o),
// each [4][512][512] f32 [K][N] -> bf16 [N][K].  grid (8,8,32).
// ---------------------------------------------------------------------------
struct P8i { const float* p[8]; };
struct P8o { u16* p[8]; };

__global__ __launch_bounds__(256) void transpose_b8(P8i in, P8o out)
{
  __shared__ float tile[64 * 65];
  const int m = blockIdx.z;
  const int set = m >> 2, layer = m & 3;
  const float* src = in.p[set] + (size_t)layer * 512 * 512;
  u16* dst = out.p[set] + (size_t)layer * 512 * 512;
  const int n0 = blockIdx.x * 64, k0 = blockIdx.y * 64;
  const int t = threadIdx.x;
#pragma unroll
  for (int p = 0; p < 16; ++p) {
    const int e = t + p * 256;
    const int lk = e >> 6, ln = e & 63;
    tile[lk * 65 + ln] = src[(size_t)(k0 + lk) * 512 + n0 + ln];
  }
  __syncthreads();
#pragma unroll
  for (int p = 0; p < 16; ++p) {
    const int e = t + p * 256;
    const int ln = e >> 6, lk = e & 63;
    dst[(size_t)(n0 + ln) * 512 + k0 + lk] = f2bf(tile[lk * 65 + ln]);
  }
}

__global__ __launch_bounds__(256) void transpose_f2b(
    const float* __restrict__ in, u16* __restrict__ out, int K, int N)
{
  __shared__ float tile[64 * 65];
  const size_t mat = (size_t)blockIdx.z * K * N;
  const int n0 = blockIdx.x * 64, k0 = blockIdx.y * 64;
  const int t = threadIdx.x;
#pragma unroll
  for (int p = 0; p < 16; ++p) {
    const int e = t + p * 256;
    const int lk = e >> 6, ln = e & 63;
    tile[lk * 65 + ln] = in[mat + (size_t)(k0 + lk) * N + n0 + ln];
  }
  __syncthreads();
#pragma unroll
  for (int p = 0; p < 16; ++p) {
    const int e = t + p * 256;
    const int ln = e >> 6, lk = e & 63;
    out[mat + (size_t)(n0 + ln) * K + k0 + lk] = f2bf(tile[lk * 65 + ln]);
  }
}

// f32 -> (optional f32 copy) + bf16
__global__ __launch_bounds__(256) void cast_dual(
    const float* __restrict__ in, float* __restrict__ fout, u16* __restrict__ bout)
{
  const int i = blockIdx.x * 256 + threadIdx.x;
  const float4 a = ((const float4*)in)[i * 2];
  const float4 b = ((const float4*)in)[i * 2 + 1];
  if (fout) {
    ((float4*)fout)[i * 2] = a;
    ((float4*)fout)[i * 2 + 1] = b;
  }
  ((ushort4*)bout)[i * 2]     = make_ushort4(f2bf(a.x), f2bf(a.y), f2bf(a.z), f2bf(a.w));
  ((ushort4*)bout)[i * 2 + 1] = make_ushort4(f2bf(b.x), f2bf(b.y), f2bf(b.z), f2bf(b.w));
}

// ---------------------------------------------------------------------------
// Multi-segment GEMM (round-6 proven structure + z batching):
//   seg = by>>lognyb: C_s[.. + z*zC] = act_s(A_s[M][K]@Wt_s^T + b_s)
// A,Wt bf16; Wt[N][K]. 64x64 tile, BK=64, reg-staged dbuf, 1 barrier/K-step.
// lda/ldw: row strides. z strides in elements. bias applied all-z or z==0 only.
// ---------------------------------------------------------------------------
template<int CDT>
__global__ __launch_bounds__(256, 4) void gemm64(
    const u16* __restrict__ A0, const u16* __restrict__ A1, const u16* __restrict__ A2,
    const u16* __restrict__ W0, const u16* __restrict__ W1, const u16* __restrict__ W2,
    const float* __restrict__ b0, const float* __restrict__ b1, const float* __restrict__ b2,
    void* __restrict__ C0, void* __restrict__ C1, void* __restrict__ C2,
    int acts, int N, int K, int lda, int ldw, int lognyb,
    i64 zA, i64 zW, i64 zB, i64 zC, int biasAllZ)
{
  constexpr int LDT = 72;
  __shared__ __align__(16) u16 As[2][64 * LDT];
  __shared__ __align__(16) u16 Bs[2][64 * LDT];
  const int tid = threadIdx.x;
  const int by = blockIdx.y;
  const int z = blockIdx.z;
  const int seg = by >> lognyb;
  const int ny = by & ((1 << lognyb) - 1);
  const u16* A = (seg == 0 ? A0 : (seg == 1 ? A1 : A2)) + (size_t)z * zA;
  const u16* W = (seg == 0 ? W0 : (seg == 1 ? W1 : W2)) + (size_t)z * zW;
  const float* bias = (seg == 0 ? b0 : (seg == 1 ? b1 : b2)) + (size_t)z * zB;
  void* Cv = seg == 0 ? C0 : (seg == 1 ? C1 : C2);
  const int act = (acts >> (2 * seg)) & 3;
  const bool dobias = biasAllZ || (z == 0);

  const int bm0 = blockIdx.x * 64, bn0 = ny * 64;
  const int lane = tid & 63, wid = tid >> 6;
  const int wr = wid >> 1, wc = wid & 1;
  const int l15 = lane & 15, lg = lane >> 4;
  const int srow = tid >> 2, scg = (tid & 3) * 16;
  const u16* Ap = A + (size_t)(bm0 + srow) * lda + scg;
  const u16* Wp = W + (size_t)(bn0 + srow) * ldw + scg;

  uint4 ra0 = *(const uint4*)(Ap);
  uint4 ra1 = *(const uint4*)(Ap + 8);
  uint4 rb0 = *(const uint4*)(Wp);
  uint4 rb1 = *(const uint4*)(Wp + 8);
  *(uint4*)&As[0][srow * LDT + scg]     = ra0;
  *(uint4*)&As[0][srow * LDT + scg + 8] = ra1;
  *(uint4*)&Bs[0][srow * LDT + scg]     = rb0;
  *(uint4*)&Bs[0][srow * LDT + scg + 8] = rb1;
  __syncthreads();

  f32x4v acc[2][2] = {};
  int cur = 0;
  for (int k0 = 0; k0 < K; k0 += 64) {
    const bool more = (k0 + 64 < K);
    if (more) {
      ra0 = *(const uint4*)(Ap + k0 + 64);
      ra1 = *(const uint4*)(Ap + k0 + 72);
      rb0 = *(const uint4*)(Wp + k0 + 64);
      rb1 = *(const uint4*)(Wp + k0 + 72);
    }
    bf16x8 af[2][2], bw[2][2];
#pragma unroll
    for (int kk = 0; kk < 2; ++kk) {
#pragma unroll
      for (int mm = 0; mm < 2; ++mm)
        af[kk][mm] = *(const bf16x8*)&As[cur][(wr * 32 + mm * 16 + l15) * LDT + kk * 32 + lg * 8];
#pragma unroll
      for (int nn = 0; nn < 2; ++nn)
        bw[kk][nn] = *(const bf16x8*)&Bs[cur][(wc * 32 + nn * 16 + l15) * LDT + kk * 32 + lg * 8];
    }
#pragma unroll
    for (int kk = 0; kk < 2; ++kk)
#pragma unroll
      for (int mm = 0; mm < 2; ++mm)
#pragma unroll
        for (int nn = 0; nn < 2; ++nn)
          acc[mm][nn] = __builtin_amdgcn_mfma_f32_16x16x32_bf16(af[kk][mm], bw[kk][nn], acc[mm][nn], 0, 0, 0);
    if (more) {
      *(uint4*)&As[cur ^ 1][srow * LDT + scg]     = ra0;
      *(uint4*)&As[cur ^ 1][srow * LDT + scg + 8] = ra1;
      *(uint4*)&Bs[cur ^ 1][srow * LDT + scg]     = rb0;
      *(uint4*)&Bs[cur ^ 1][srow * LDT + scg + 8] = rb1;
    }
    __syncthreads();
    cur ^= 1;
  }
#pragma unroll
  for (int nn = 0; nn < 2; ++nn) {
    const int col = bn0 + wc * 32 + nn * 16 + l15;
    const float bv = dobias ? bias[col] : 0.f;
#pragma unroll
    for (int mm = 0; mm < 2; ++mm) {
#pragma unroll
      for (int r = 0; r < 4; ++r) {
        const int row = bm0 + wr * 32 + mm * 16 + lg * 4 + r;
        float v = acc[mm][nn][r] + bv;
        if (act == 1) v = v > 0.f ? v + 1.f : __expf(v);
        else if (act == 2) v = 0.5f * v * (1.f + erff(v * 0.70710678f));
        const size_t idx = (size_t)row * N + col + (size_t)z * zC;
        if (CDT == 0) ((float*)Cv)[idx] = v;
        else          ((u16*)Cv)[idx] = f2bf(v);
      }
    }
  }
}

// ---------------------------------------------------------------------------
// Chunk sums (MFMA), z-batched over layers: KVt[m][d] = sum_s V[s][m]*K[s][d],
// z[d] = sum_s K[s][d].  Inputs bf16.
// ---------------------------------------------------------------------------
__global__ __launch_bounds__(256) void lin_chunk_mfma(
    const u16* __restrict__ kbuf, const u16* __restrict__ vbuf,
    float* __restrict__ KVc, float* __restrict__ zc)
{
  constexpr int LDT = 72;
  __shared__ __align__(16) u16 Kt[64 * LDT];   // Kt[d][s]
  __shared__ __align__(16) u16 Vt[64 * LDT];   // Vt[m][s]
  const int c = blockIdx.x, bh = blockIdx.y, zl = blockIdx.z;
  kbuf += (size_t)zl * 2048 * 512;
  vbuf += (size_t)zl * 2048 * 512;
  KVc  += (size_t)zl * 16 * 16 * 4096;
  zc   += (size_t)zl * 16 * 16 * 64;
  const int b = bh >> 3, h = bh & 7;
  const int t = threadIdx.x;
  const size_t rowbase = (size_t)(b * 1024 + c * 64);
  const int sp = t >> 4, colq = (t & 15) * 4;
#pragma unroll
  for (int pp = 0; pp < 2; ++pp) {
    const int s0 = pp * 32 + 2 * sp;
    const ushort4 ka = *(const ushort4*)&kbuf[(rowbase + s0) * 512 + h * 64 + colq];
    const ushort4 kb_ = *(const ushort4*)&kbuf[(rowbase + s0 + 1) * 512 + h * 64 + colq];
    const ushort4 va = *(const ushort4*)&vbuf[(rowbase + s0) * 512 + h * 64 + colq];
    const ushort4 vb_ = *(const ushort4*)&vbuf[(rowbase + s0 + 1) * 512 + h * 64 + colq];
    *(unsigned*)&Kt[(colq + 0) * LDT + s0] = (unsigned)ka.x | ((unsigned)kb_.x << 16);
    *(unsigned*)&Kt[(colq + 1) * LDT + s0] = (unsigned)ka.y | ((unsigned)kb_.y << 16);
    *(unsigned*)&Kt[(colq + 2) * LDT + s0] = (unsigned)ka.z | ((unsigned)kb_.z << 16);
    *(unsigned*)&Kt[(colq + 3) * LDT + s0] = (unsigned)ka.w | ((unsigned)kb_.w << 16);
    *(unsigned*)&Vt[(colq + 0) * LDT + s0] = (unsigned)va.x | ((unsigned)vb_.x << 16);
    *(unsigned*)&Vt[(colq + 1) * LDT + s0] = (unsigned)va.y | ((unsigned)vb_.y << 16);
    *(unsigned*)&Vt[(colq + 2) * LDT + s0] = (unsigned)va.z | ((unsigned)vb_.z << 16);
    *(unsigned*)&Vt[(colq + 3) * LDT + s0] = (unsigned)va.w | ((unsigned)vb_.w << 16);
  }
  __syncthreads();
  {
    const int zd = t >> 2, zg = t & 3;
    float zp = 0.f;
#pragma unroll
    for (int ss = 0; ss < 16; ++ss) zp += bf2f(Kt[zd * LDT + zg * 16 + ss]);
    zp += __shfl_xor(zp, 1, 64);
    zp += __shfl_xor(zp, 2, 64);
    if (zg == 0) zc[(size_t)(bh * 16 + c) * 64 + zd] = zp;
  }
  const int lane = t & 63, wid = t >> 6;
  const int wr = wid >> 1, wc = wid & 1;
  const int l15 = lane & 15, lg = lane >> 4;
  bf16x8 av[2][2], bk[2][2];
#pragma unroll
  for (int kk = 0; kk < 2; ++kk) {
#pragma unroll
    for (int mm = 0; mm < 2; ++mm)
      av[kk][mm] = *(const bf16x8*)&Vt[(wr * 32 + mm * 16 + l15) * LDT + kk * 32 + lg * 8];
#pragma unroll
    for (int nn = 0; nn < 2; ++nn)
      bk[kk][nn] = *(const bf16x8*)&Kt[(wc * 32 + nn * 16 + l15) * LDT + kk * 32 + lg * 8];
  }
  f32x4v acc[2][2] = {};
#pragma unroll
  for (int kk = 0; kk < 2; ++kk)
#pragma unroll
    for (int mm = 0; mm < 2; ++mm)
#pragma unroll
      for (int nn = 0; nn < 2; ++nn)
        acc[mm][nn] = __builtin_amdgcn_mfma_f32_16x16x32_bf16(av[kk][mm], bk[kk][nn], acc[mm][nn], 0, 0, 0);
  float* kvout = KVc + (size_t)(bh * 16 + c) * 4096;
#pragma unroll
  for (int mm = 0; mm < 2; ++mm)
#pragma unroll
    for (int r = 0; r < 4; ++r) {
      const int row = wr * 32 + mm * 16 + lg * 4 + r;
#pragma unroll
      for (int nn = 0; nn < 2; ++nn) {
        const int col = wc * 32 + nn * 16 + l15;
        kvout[row * 64 + col] = acc[mm][nn][r];
      }
    }
}

// ---------------------------------------------------------------------------
// SA apply (MFMA): prefix-sums KVc/zc chunks [0,c) in-kernel, then
// S=Q@K^T masked; O = S@V + Q@KVprefix; den = rowsum(S)+Q.zp.  bf16 in/out.
// ---------------------------------------------------------------------------
__global__ __launch_bounds__(256) void sa_apply_mfma(
    const u16* __restrict__ qbuf, const u16* __restrict__ kbuf,
    const u16* __restrict__ vbuf, const float* __restrict__ KVc,
    const float* __restrict__ zc, u16* __restrict__ out)
{
  constexpr int LDT = 72;
  __shared__ __align__(16) u16 Qs[64 * LDT];
  __shared__ __align__(16) u16 Ks[64 * LDT];
  __shared__ __align__(16) u16 Vt[64 * LDT];
  __shared__ __align__(16) u16 Ps[64 * LDT];
  __shared__ __align__(16) u16 KVs[64 * LDT];
  __shared__ float zp[64];
  __shared__ float den1[2][64];
  __shared__ float den2[64];
  const int c = blockIdx.x, bh = blockIdx.y;
  const int b = bh >> 3, h = bh & 7;
  const int t = threadIdx.x;
  const size_t rowbase = (size_t)(b * 1024 + c * 64);
  {
    const int srow = t >> 2, scg = (t & 3) * 16;
    *(uint4*)&Qs[srow * LDT + scg]     = *(const uint4*)&qbuf[(rowbase + srow) * 512 + h * 64 + scg];
    *(uint4*)&Qs[srow * LDT + scg + 8] = *(const uint4*)&qbuf[(rowbase + srow) * 512 + h * 64 + scg + 8];
    *(uint4*)&Ks[srow * LDT + scg]     = *(const uint4*)&kbuf[(rowbase + srow) * 512 + h * 64 + scg];
    *(uint4*)&Ks[srow * LDT + scg + 8] = *(const uint4*)&kbuf[(rowbase + srow) * 512 + h * 64 + scg + 8];
    const float* kvbase = KVc + (size_t)(bh * 16) * 4096 + srow * 64 + scg;
    float4 s0 = make_float4(0, 0, 0, 0), s1 = s0, s2 = s0, s3 = s0;
    for (int cc = 0; cc < c; ++cc) {
      const float* p = kvbase + (size_t)cc * 4096;
      const float4 a0 = *(const float4*)&p[0];
      const float4 a1 = *(const float4*)&p[4];
      const float4 a2 = *(const float4*)&p[8];
      const float4 a3 = *(const float4*)&p[12];
      s0.x += a0.x; s0.y += a0.y; s0.z += a0.z; s0.w += a0.w;
      s1.x += a1.x; s1.y += a1.y; s1.z += a1.z; s1.w += a1.w;
      s2.x += a2.x; s2.y += a2.y; s2.z += a2.z; s2.w += a2.w;
      s3.x += a3.x; s3.y += a3.y; s3.z += a3.z; s3.w += a3.w;
    }
    *(ushort4*)&KVs[srow * LDT + scg + 0]  = make_ushort4(f2bf(s0.x), f2bf(s0.y), f2bf(s0.z), f2bf(s0.w));
    *(ushort4*)&KVs[srow * LDT + scg + 4]  = make_ushort4(f2bf(s1.x), f2bf(s1.y), f2bf(s1.z), f2bf(s1.w));
    *(ushort4*)&KVs[srow * LDT + scg + 8]  = make_ushort4(f2bf(s2.x), f2bf(s2.y), f2bf(s2.z), f2bf(s2.w));
    *(ushort4*)&KVs[srow * LDT + scg + 12] = make_ushort4(f2bf(s3.x), f2bf(s3.y), f2bf(s3.z), f2bf(s3.w));
  }
  {
    const int sp = t >> 4, colq = (t & 15) * 4;
#pragma unroll
    for (int pp = 0; pp < 2; ++pp) {
      const int s0 = pp * 32 + 2 * sp;
      const ushort4 va = *(const ushort4*)&vbuf[(rowbase + s0) * 512 + h * 64 + colq];
      const ushort4 vb_ = *(const ushort4*)&vbuf[(rowbase + s0 + 1) * 512 + h * 64 + colq];
      *(unsigned*)&Vt[(colq + 0) * LDT + s0] = (unsigned)va.x | ((unsigned)vb_.x << 16);
      *(unsigned*)&Vt[(colq + 1) * LDT + s0] = (unsigned)va.y | ((unsigned)vb_.y << 16);
      *(unsigned*)&Vt[(colq + 2) * LDT + s0] = (unsigned)va.z | ((unsigned)vb_.z << 16);
      *(unsigned*)&Vt[(colq + 3) * LDT + s0] = (unsigned)va.w | ((unsigned)vb_.w << 16);
    }
  }
  if (t < 64) {
    float z = 0.f;
    for (int cc = 0; cc < c; ++cc) z += zc[(size_t)(bh * 16 + cc) * 64 + t];
    zp[t] = z;
  }
  __syncthreads();
  {
    const int di = t >> 2, dg = t & 3;
    float p2 = 0.f;
#pragma unroll
    for (int dd = 0; dd < 16; ++dd)
      p2 += bf2f(Qs[di * LDT + dg * 16 + dd]) * zp[dg * 16 + dd];
    p2 += __shfl_xor(p2, 1, 64);
    p2 += __shfl_xor(p2, 2, 64);
    if (dg == 0) den2[di] = p2;
  }
  const int lane = t & 63, wid = t >> 6;
  const int wr = wid >> 1, wc = wid & 1;
  const int l15 = lane & 15, lg = lane >> 4;
  bf16x8 af_q[2][2], bx[2][2];
#pragma unroll
  for (int kk = 0; kk < 2; ++kk) {
#pragma unroll
    for (int mm = 0; mm < 2; ++mm)
      af_q[kk][mm] = *(const bf16x8*)&Qs[(wr * 32 + mm * 16 + l15) * LDT + kk * 32 + lg * 8];
#pragma unroll
    for (int nn = 0; nn < 2; ++nn)
      bx[kk][nn] = *(const bf16x8*)&Ks[(wc * 32 + nn * 16 + l15) * LDT + kk * 32 + lg * 8];
  }
  f32x4v s_acc[2][2] = {};
#pragma unroll
  for (int kk = 0; kk < 2; ++kk)
#pragma unroll
    for (int mm = 0; mm < 2; ++mm)
#pragma unroll
      for (int nn = 0; nn < 2; ++nn)
        s_acc[mm][nn] = __builtin_amdgcn_mfma_f32_16x16x32_bf16(af_q[kk][mm], bx[kk][nn], s_acc[mm][nn], 0, 0, 0);
#pragma unroll
  for (int mm = 0; mm < 2; ++mm)
#pragma unroll
    for (int r = 0; r < 4; ++r) {
      const int row = wr * 32 + mm * 16 + lg * 4 + r;
      float dsum = 0.f;
#pragma unroll
      for (int nn = 0; nn < 2; ++nn) {
        const int col = wc * 32 + nn * 16 + l15;
        const float val = (col <= row) ? s_acc[mm][nn][r] : 0.f;
        Ps[row * LDT + col] = f2bf(val);
        dsum += val;
      }
      dsum += __shfl_xor(dsum, 1, 64);
      dsum += __shfl_xor(dsum, 2, 64);
      dsum += __shfl_xor(dsum, 4, 64);
      dsum += __shfl_xor(dsum, 8, 64);
      if (l15 == 0) den1[wc][row] = dsum;
    }
  __syncthreads();
  bf16x8 ap[2][2];
#pragma unroll
  for (int kk = 0; kk < 2; ++kk) {
#pragma unroll
    for (int mm = 0; mm < 2; ++mm)
      ap[kk][mm] = *(const bf16x8*)&Ps[(wr * 32 + mm * 16 + l15) * LDT + kk * 32 + lg * 8];
#pragma unroll
    for (int nn = 0; nn < 2; ++nn)
      bx[kk][nn] = *(const bf16x8*)&Vt[(wc * 32 + nn * 16 + l15) * LDT + kk * 32 + lg * 8];
  }
  f32x4v o_acc[2][2] = {};
#pragma unroll
  for (int kk = 0; kk < 2; ++kk)
#pragma unroll
    for (int mm = 0; mm < 2; ++mm)
#pragma unroll
      for (int nn = 0; nn < 2; ++nn)
        o_acc[mm][nn] = __builtin_amdgcn_mfma_f32_16x16x32_bf16(ap[kk][mm], bx[kk][nn], o_acc[mm][nn], 0, 0, 0);
#pragma unroll
  for (int kk = 0; kk < 2; ++kk)
#pragma unroll
    for (int nn = 0; nn < 2; ++nn)
      bx[kk][nn] = *(const bf16x8*)&KVs[(wc * 32 + nn * 16 + l15) * LDT + kk * 32 + lg * 8];
#pragma unroll
  for (int kk = 0; kk < 2; ++kk)
#pragma unroll
    for (int mm = 0; mm < 2; ++mm)
#pragma unroll
      for (int nn = 0; nn < 2; ++nn)
        o_acc[mm][nn] = __builtin_amdgcn_mfma_f32_16x16x32_bf16(af_q[kk][mm], bx[kk][nn], o_acc[mm][nn], 0, 0, 0);
#pragma unroll
  for (int mm = 0; mm < 2; ++mm)
#pragma unroll
    for (int r = 0; r < 4; ++r) {
      const int row = wr * 32 + mm * 16 + lg * 4 + r;
      const float rden = 1.f / (den1[0][row] + den1[1][row] + den2[row] + 1e-6f);
#pragma unroll
      for (int nn = 0; nn < 2; ++nn) {
        const int col = wc * 32 + nn * 16 + l15;
        out[(rowbase + row) * 512 + h * 64 + col] = f2bf(o_acc[mm][nn][r] * rden);
      }
    }
}

// ---------------------------------------------------------------------------
// CA apply (MFMA): sums 16 chunk partials in-kernel; O = Q@KVtot / den.
// ---------------------------------------------------------------------------
__global__ __launch_bounds__(256) void ca_apply_mfma(
    const u16* __restrict__ qbuf, const float* __restrict__ KVc,
    const float* __restrict__ zc, u16* __restrict__ out)
{
  constexpr int LDT = 72;
  __shared__ __align__(16) u16 Qs[64 * LDT];
  __shared__ __align__(16) u16 KVs[64 * LDT];
  __shared__ float zt[64];
  __shared__ float den2[64];
  const int c = blockIdx.x, bh = blockIdx.y;
  const int b = bh >> 3, h = bh & 7;
  const int t = threadIdx.x;
  const size_t rowbase = (size_t)(b * 1024 + c * 64);
  {
    const int srow = t >> 2, scg = (t & 3) * 16;
    *(uint4*)&Qs[srow * LDT + scg]     = *(const uint4*)&qbuf[(rowbase + srow) * 512 + h * 64 + scg];
    *(uint4*)&Qs[srow * LDT + scg + 8] = *(const uint4*)&qbuf[(rowbase + srow) * 512 + h * 64 + scg + 8];
    const float* kvbase = KVc + (size_t)(bh * 16) * 4096 + srow * 64 + scg;
    float4 s0 = make_float4(0, 0, 0, 0), s1 = s0, s2 = s0, s3 = s0;
    for (int cc = 0; cc < 16; ++cc) {
      const float* p = kvbase + (size_t)cc * 4096;
      const float4 a0 = *(const float4*)&p[0];
      const float4 a1 = *(const float4*)&p[4];
      const float4 a2 = *(const float4*)&p[8];
      const float4 a3 = *(const float4*)&p[12];
      s0.x += a0.x; s0.y += a0.y; s0.z += a0.z; s0.w += a0.w;
      s1.x += a1.x; s1.y += a1.y; s1.z += a1.z; s1.w += a1.w;
      s2.x += a2.x; s2.y += a2.y; s2.z += a2.z; s2.w += a2.w;
      s3.x += a3.x; s3.y += a3.y; s3.z += a3.z; s3.w += a3.w;
    }
    *(ushort4*)&KVs[srow * LDT + scg + 0]  = make_ushort4(f2bf(s0.x), f2bf(s0.y), f2bf(s0.z), f2bf(s0.w));
    *(ushort4*)&KVs[srow * LDT + scg + 4]  = make_ushort4(f2bf(s1.x), f2bf(s1.y), f2bf(s1.z), f2bf(s1.w));
    *(ushort4*)&KVs[srow * LDT + scg + 8]  = make_ushort4(f2bf(s2.x), f2bf(s2.y), f2bf(s2.z), f2bf(s2.w));
    *(ushort4*)&KVs[srow * LDT + scg + 12] = make_ushort4(f2bf(s3.x), f2bf(s3.y), f2bf(s3.z), f2bf(s3.w));
  }
  if (t < 64) {
    float z = 0.f;
    for (int cc = 0; cc < 16; ++cc) z += zc[(size_t)(bh * 16 + cc) * 64 + t];
    zt[t] = z;
  }
  __syncthreads();
  {
    const int di = t >> 2, dg = t & 3;
    float p2 = 0.f;
#pragma unroll
    for (int dd = 0; dd < 16; ++dd)
      p2 += bf2f(Qs[di * LDT + dg * 16 + dd]) * zt[dg * 16 + dd];
    p2 += __shfl_xor(p2, 1, 64);
    p2 += __shfl_xor(p2, 2, 64);
    if (dg == 0) den2[di] = p2;
  }
  const int lane = t & 63, wid = t >> 6;
  const int wr = wid >> 1, wc = wid & 1;
  const int l15 = lane & 15, lg = lane >> 4;
  bf16x8 aq[2][2], bkv[2][2];
#pragma unroll
  for (int kk = 0; kk < 2; ++kk) {
#pragma unroll
    for (int mm = 0; mm < 2; ++mm)
      aq[kk][mm] = *(const bf16x8*)&Qs[(wr * 32 + mm * 16 + l15) * LDT + kk * 32 + lg * 8];
#pragma unroll
    for (int nn = 0; nn < 2; ++nn)
      bkv[kk][nn] = *(const bf16x8*)&KVs[(wc * 32 + nn * 16 + l15) * LDT + kk * 32 + lg * 8];
  }
  f32x4v o_acc[2][2] = {};
#pragma unroll
  for (int kk = 0; kk < 2; ++kk)
#pragma unroll
    for (int mm = 0; mm < 2; ++mm)
#pragma unroll
      for (int nn = 0; nn < 2; ++nn)
        o_acc[mm][nn] = __builtin_amdgcn_mfma_f32_16x16x32_bf16(aq[kk][mm], bkv[kk][nn], o_acc[mm][nn], 0, 0, 0);
  __syncthreads();
#pragma unroll
  for (int mm = 0; mm < 2; ++mm)
#pragma unroll
    for (int r = 0; r < 4; ++r) {
      const int row = wr * 32 + mm * 16 + lg * 4 + r;
      const float rden = 1.f / (den2[row] + 1e-6f);
#pragma unroll
      for (int nn = 0; nn < 2; ++nn) {
        const int col = wc * 32 + nn * 16 + l15;
        out[(rowbase + row) * 512 + h * 64 + col] = f2bf(o_acc[mm][nn][r] * rden);
      }
    }
}

// ---------------------------------------------------------------------------
// LayerNorm: x = LN(x + sum_p a_p) in place (f32) + bf16 mirror xb.
// ---------------------------------------------------------------------------
template<int NPART>
__global__ __launch_bounds__(256) void ln_residual(
    float* __restrict__ x, const float* __restrict__ a, i64 pstride,
    const float* __restrict__ g, const float* __restrict__ bt,
    u16* __restrict__ xb)
{
  const int t = threadIdx.x, lane = t & 63, w = t >> 6;
  const int row = blockIdx.x * 4 + w;
  float* xr = x + (size_t)row * 512;
  float4 x0 = *(const float4*)&xr[lane * 8];
  float4 x1 = *(const float4*)&xr[lane * 8 + 4];
  float v[8] = { x0.x, x0.y, x0.z, x0.w, x1.x, x1.y, x1.z, x1.w };
#pragma unroll
  for (int p = 0; p < NPART; ++p) {
    const float* ar = a + (size_t)p * pstride + (size_t)row * 512;
    float4 a0 = *(const float4*)&ar[lane * 8];
    float4 a1 = *(const float4*)&ar[lane * 8 + 4];
    v[0] += a0.x; v[1] += a0.y; v[2] += a0.z; v[3] += a0.w;
    v[4] += a1.x; v[5] += a1.y; v[6] += a1.z; v[7] += a1.w;
  }
  float s = 0.f, sq = 0.f;
#pragma unroll
  for (int i = 0; i < 8; ++i) { s += v[i]; sq += v[i] * v[i]; }
#pragma unroll
  for (int off = 32; off > 0; off >>= 1) {
    s += __shfl_xor(s, off, 64);
    sq += __shfl_xor(sq, off, 64);
  }
  const float mean = s * (1.f / 512.f);
  const float var = sq * (1.f / 512.f) - mean * mean;
  const float rstd = rsqrtf(var + 1e-5f);
  float o[8];
#pragma unroll
  for (int i = 0; i < 8; ++i) {
    const int col = lane * 8 + i;
    o[i] = (v[i] - mean) * rstd * g[col] + bt[col];
  }
  *(float4*)&xr[lane * 8]     = make_float4(o[0], o[1], o[2], o[3]);
  *(float4*)&xr[lane * 8 + 4] = make_float4(o[4], o[5], o[6], o[7]);
  *(ushort4*)&xb[(size_t)row * 512 + lane * 8]     = make_ushort4(f2bf(o[0]), f2bf(o[1]), f2bf(o[2]), f2bf(o[3]));
  *(ushort4*)&xb[(size_t)row * 512 + lane * 8 + 4] = make_ushort4(f2bf(o[4]), f2bf(o[5]), f2bf(o[6]), f2bf(o[7]));
}

__global__ __launch_bounds__(256) void ln_final(
    const float* __restrict__ x, const float* __restrict__ g,
    const float* __restrict__ bt, float* __restrict__ out)
{
  const int t = threadIdx.x, lane = t & 63, w = t >> 6;
  const int row = blockIdx.x * 4 + w;
  const float* xr = x + (size_t)row * 512;
  float4 x0 = *(const float4*)&xr[lane * 8];
  float4 x1 = *(const float4*)&xr[lane * 8 + 4];
  float v[8] = { x0.x, x0.y, x0.z, x0.w, x1.x, x1.y, x1.z, x1.w };
  float s = 0.f, sq = 0.f;
#pragma unroll
  for (int i = 0; i < 8; ++i) { s += v[i]; sq += v[i] * v[i]; }
#pragma unroll
  for (int off = 32; off > 0; off >>= 1) {
    s += __shfl_xor(s, off, 64);
    sq += __shfl_xor(sq, off, 64);
  }
  const float mean = s * (1.f / 512.f);
  const float var = sq * (1.f / 512.f) - mean * mean;
  const float rstd = rsqrtf(var + 1e-5f);
  float o[8];
#pragma unroll
  for (int i = 0; i < 8; ++i) {
    const int col = lane * 8 + i;
    o[i] = (v[i] - mean) * rstd * g[col] + bt[col];
  }
  *(float4*)&out[(size_t)row * 512 + lane * 8]     = make_float4(o[0], o[1], o[2], o[3]);
  *(float4*)&out[(size_t)row * 512 + lane * 8 + 4] = make_float4(o[4], o[5], o[6], o[7]);
}

// ---------------------------------------------------------------------------
extern "C" void kernel_launch(void* const* d_in, const int* in_sizes, int n_in,
                              void* d_out, int out_size, void* d_ws, size_t ws_size,
                              hipStream_t stream)
{
  (void)in_sizes; (void)n_in; (void)out_size; (void)ws_size;
  constexpr int Dm = 512, Lc = 4, FFc = 2048;
  constexpr i64 TOK = 2048LL * 512;

  const float* memory = (const float*)d_in[0];
  const float* target = (const float*)d_in[1];
  const float *saW[4], *sab[4], *caW[4], *cab[4];
  for (int j = 0; j < 4; ++j) {
    saW[j] = (const float*)d_in[2 + 2 * j];
    sab[j] = (const float*)d_in[3 + 2 * j];
    caW[j] = (const float*)d_in[10 + 2 * j];
    cab[j] = (const float*)d_in[11 + 2 * j];
  }
  const float* ffW1 = (const float*)d_in[18];
  const float* ffb1 = (const float*)d_in[19];
  const float* ffW2 = (const float*)d_in[20];
  const float* ffb2 = (const float*)d_in[21];
  const float* lng[4] = { (const float*)d_in[22], (const float*)d_in[24],
                          (const float*)d_in[26], (const float*)d_in[28] };
  const float* lnb[4] = { (const float*)d_in[23], (const float*)d_in[25],
                          (const float*)d_in[27], (const float*)d_in[29] };

  size_t off = 0;
  auto alloc = [&](size_t bytes) -> void* {
    void* p = (char*)d_ws + off;
    off += (bytes + 255) & ~(size_t)255;
    return p;
  };
  u16* WtS[4]; u16* WtC[4];
  for (int j = 0; j < 4; ++j) WtS[j] = (u16*)alloc((size_t)Lc * Dm * Dm * 2);
  for (int j = 0; j < 4; ++j) WtC[j] = (u16*)alloc((size_t)Lc * Dm * Dm * 2);
  u16* WtF1 = (u16*)alloc((size_t)Lc * Dm * FFc * 2);
  u16* WtF2 = (u16*)alloc((size_t)Lc * FFc * Dm * 2);
  float* x     = (float*)alloc(TOK * 4);
  u16*   xb    = (u16*)alloc(TOK * 2);
  u16*   memb  = (u16*)alloc(TOK * 2);
  u16*   qh    = (u16*)alloc(TOK * 2);
  u16*   kh    = (u16*)alloc(TOK * 2);
  u16*   vh    = (u16*)alloc(TOK * 2);
  u16*   khAll = (u16*)alloc((size_t)Lc * TOK * 2);       // 8 MB
  u16*   vhAll = (u16*)alloc((size_t)Lc * TOK * 2);       // 8 MB
  float* resid = (float*)alloc((size_t)4 * TOK * 4);      // 16 MB (4 split-K partials)
  u16*   attn  = (u16*)alloc(TOK * 2);
  u16*   ffh   = (u16*)alloc((size_t)2048 * 2048 * 2);
  float* KVc   = (float*)alloc((size_t)16 * 16 * 4096 * 4);
  float* zcb   = (float*)alloc((size_t)16 * 16 * 64 * 4);
  float* KVcA  = (float*)alloc((size_t)Lc * 16 * 16 * 4096 * 4);  // 16 MB
  float* zcbA  = (float*)alloc((size_t)Lc * 16 * 16 * 64 * 4);

  {
    P8i pin; P8o pout;
    for (int j = 0; j < 4; ++j) { pin.p[j] = saW[j]; pout.p[j] = WtS[j]; }
    for (int j = 0; j < 4; ++j) { pin.p[4 + j] = caW[j]; pout.p[4 + j] = WtC[j]; }
    transpose_b8<<<dim3(8, 8, 32), 256, 0, stream>>>(pin, pout);
  }
  transpose_f2b<<<dim3(32, 8, 4), 256, 0, stream>>>(ffW1, WtF1, Dm, FFc);
  transpose_f2b<<<dim3(8, 32, 4), 256, 0, stream>>>(ffW2, WtF2, FFc, Dm);

  cast_dual<<<512, 256, 0, stream>>>(target, x, xb);
  cast_dual<<<512, 256, 0, stream>>>(memory, nullptr, memb);

  // ---- hoisted: CA K/V projections for ALL layers (grid 2048 blocks) ----
  gemm64<1><<<dim3(32, 16, 4), 256, 0, stream>>>(
      memb, memb, memb, WtC[1], WtC[2], WtC[2],
      cab[1], cab[2], cab[2], khAll, vhAll, vhAll,
      0x01 /*seg0 phi, seg1 none*/, 512, 512, 512, 512, 3,
      0, (i64)Dm * Dm, (i64)Dm, TOK, 1);
  // ---- hoisted: CA chunk sums for ALL layers ----
  lin_chunk_mfma<<<dim3(16, 16, 4), 256, 0, stream>>>(khAll, vhAll, KVcA, zcbA);

  for (int i = 0; i < Lc; ++i) {
    const size_t wo  = (size_t)i * Dm * Dm;
    const size_t wo1 = (size_t)i * Dm * FFc;
    const size_t wo2 = (size_t)i * FFc * Dm;
    // ---- causal linear self-attention ----
    gemm64<1><<<dim3(32, 24), 256, 0, stream>>>(
        xb, xb, xb, WtS[0] + wo, WtS[1] + wo, WtS[2] + wo,
        sab[0] + i * Dm, sab[1] + i * Dm, sab[2] + i * Dm,
        qh, kh, vh, 0x05, 512, 512, 512, 512, 3, 0, 0, 0, 0, 1);
    lin_chunk_mfma<<<dim3(16, 16), 256, 0, stream>>>(kh, vh, KVc, zcb);
    sa_apply_mfma<<<dim3(16, 16), 256, 0, stream>>>(qh, kh, vh, KVc, zcb, attn);
    gemm64<0><<<dim3(32, 8), 256, 0, stream>>>(
        attn, attn, attn, WtS[3] + wo, WtS[3] + wo, WtS[3] + wo,
        sab[3] + i * Dm, sab[3] + i * Dm, sab[3] + i * Dm,
        resid, resid, resid, 0, 512, 512, 512, 512, 3, 0, 0, 0, 0, 1);
    ln_residual<1><<<512, 256, 0, stream>>>(x, resid, TOK, lng[0] + i * Dm, lnb[0] + i * Dm, xb);
    // ---- linear cross-attention (K/V + chunks precomputed) ----
    gemm64<1><<<dim3(32, 8), 256, 0, stream>>>(
        xb, xb, xb, WtC[0] + wo, WtC[0] + wo, WtC[0] + wo,
        cab[0] + i * Dm, cab[0] + i * Dm, cab[0] + i * Dm,
        qh, qh, qh, 0x01, 512, 512, 512, 512, 3, 0, 0, 0, 0, 1);
    ca_apply_mfma<<<dim3(16, 16), 256, 0, stream>>>(
        qh, KVcA + (size_t)i * 16 * 16 * 4096, zcbA + (size_t)i * 16 * 16 * 64, attn);
    gemm64<0><<<dim3(32, 8), 256, 0, stream>>>(
        attn, attn, attn, WtC[3] + wo, WtC[3] + wo, WtC[3] + wo,
        cab[3] + i * Dm, cab[3] + i * Dm, cab[3] + i * Dm,
        resid, resid, resid, 0, 512, 512, 512, 512, 3, 0, 0, 0, 0, 1);
    ln_residual<1><<<512, 256, 0, stream>>>(x, resid, TOK, lng[1] + i * Dm, lnb[1] + i * Dm, xb);
    // ---- FFN (FFN2 split-K=4 into resid partials) ----
    gemm64<1><<<dim3(32, 32), 256, 0, stream>>>(
        xb, xb, xb, WtF1 + wo1, WtF1 + wo1, WtF1 + wo1,
        ffb1 + i * FFc, ffb1 + i * FFc, ffb1 + i * FFc,
        ffh, ffh, ffh, 2, 2048, 512, 512, 512, 5, 0, 0, 0, 0, 1);
    gemm64<0><<<dim3(32, 8, 4), 256, 0, stream>>>(
        ffh, ffh, ffh, WtF2 + wo2, WtF2 + wo2, WtF2 + wo2,
        ffb2 + i * Dm, ffb2 + i * Dm, ffb2 + i * Dm,
        resid, resid, resid, 0, 512, 512, 2048, 2048, 3,
        512, 512, 0, TOK, 0);
    ln_residual<4><<<512, 256, 0, stream>>>(x, resid, TOK, lng[2] + i * Dm, lnb[2] + i * Dm, xb);
  }
  ln_final<<<512, 256, 0, stream>>>(x, lng[3], lnb[3], (float*)d_out);
}

// Round 9
// 593.720 us; speedup vs baseline: 1.2562x; 1.0049x over previous
//
#include <hip/hip_runtime.h>
#include <hip/hip_bf16.h>
#include <math.h>

// ---------------------------------------------------------------------------
// LinearTransformerCausalDecoder on MI355X (gfx950)
// B=2, S=M=1024, D=512, H=8, HD=64, L=4, FF=2048
// d_in / d_out FLOAT32. Weights pre-transposed to bf16 Wt[N][K] once.
// GEMM: 64x64 tile, BK=64, depth-2 register pipeline (statically unrolled),
// z-stride batching + split-K. CA K/V + chunk sums hoisted across layers.
// ---------------------------------------------------------------------------

typedef unsigned short u16;
typedef __bf16 bf16x8 __attribute__((ext_vector_type(8)));
typedef float f32x4v __attribute__((ext_vector_type(4)));
typedef long long i64;

#define DEVI __device__ __forceinline__

DEVI float bf2f(u16 u) { return __uint_as_float(((unsigned)u) << 16); }
DEVI u16 f2bf(float f) {
  unsigned u = __float_as_uint(f);
  u += 0x7FFFu + ((u >> 16) & 1u);   // RNE
  return (u16)(u >> 16);
}

// ---------------------------------------------------------------------------
// Batched weight transpose+convert: 8 sets (sa q,k,v,o / ca q,k,v,o),
// each [4][512][512] f32 [K][N] -> bf16 [N][K].  grid (8,8,32).
// ---------------------------------------------------------------------------
struct P8i { const float* p[8]; };
struct P8o { u16* p[8]; };

__global__ __launch_bounds__(256) void transpose_b8(P8i in, P8o out)
{
  __shared__ float tile[64 * 65];
  const int m = blockIdx.z;
  const int set = m >> 2, layer = m & 3;
  const float* src = in.p[set] + (size_t)layer * 512 * 512;
  u16* dst = out.p[set] + (size_t)layer * 512 * 512;
  const int n0 = blockIdx.x * 64, k0 = blockIdx.y * 64;
  const int t = threadIdx.x;
#pragma unroll
  for (int p = 0; p < 16; ++p) {
    const int e = t + p * 256;
    const int lk = e >> 6, ln = e & 63;
    tile[lk * 65 + ln] = src[(size_t)(k0 + lk) * 512 + n0 + ln];
  }
  __syncthreads();
#pragma unroll
  for (int p = 0; p < 16; ++p) {
    const int e = t + p * 256;
    const int ln = e >> 6, lk = e & 63;
    dst[(size_t)(n0 + ln) * 512 + k0 + lk] = f2bf(tile[lk * 65 + ln]);
  }
}

__global__ __launch_bounds__(256) void transpose_f2b(
    const float* __restrict__ in, u16* __restrict__ out, int K, int N)
{
  __shared__ float tile[64 * 65];
  const size_t mat = (size_t)blockIdx.z * K * N;
  const int n0 = blockIdx.x * 64, k0 = blockIdx.y * 64;
  const int t = threadIdx.x;
#pragma unroll
  for (int p = 0; p < 16; ++p) {
    const int e = t + p * 256;
    const int lk = e >> 6, ln = e & 63;
    tile[lk * 65 + ln] = in[mat + (size_t)(k0 + lk) * N + n0 + ln];
  }
  __syncthreads();
#pragma unroll
  for (int p = 0; p < 16; ++p) {
    const int e = t + p * 256;
    const int ln = e >> 6, lk = e & 63;
    out[mat + (size_t)(n0 + ln) * K + k0 + lk] = f2bf(tile[lk * 65 + ln]);
  }
}

// f32 -> (optional f32 copy) + bf16
__global__ __launch_bounds__(256) void cast_dual(
    const float* __restrict__ in, float* __restrict__ fout, u16* __restrict__ bout)
{
  const int i = blockIdx.x * 256 + threadIdx.x;
  const float4 a = ((const float4*)in)[i * 2];
  const float4 b = ((const float4*)in)[i * 2 + 1];
  if (fout) {
    ((float4*)fout)[i * 2] = a;
    ((float4*)fout)[i * 2 + 1] = b;
  }
  ((ushort4*)bout)[i * 2]     = make_ushort4(f2bf(a.x), f2bf(a.y), f2bf(a.z), f2bf(a.w));
  ((ushort4*)bout)[i * 2 + 1] = make_ushort4(f2bf(b.x), f2bf(b.y), f2bf(b.z), f2bf(b.w));
}

// ---------------------------------------------------------------------------
// Multi-segment GEMM, depth-2 register pipeline, statically unrolled x2.
//   seg = by>>lognyb: C_s[.. + z*zC] = act_s(A_s[M][K]@Wt_s^T + b_s)
// A,Wt bf16; Wt[N][K]. 64x64 tile, BK=64. Requires K/64 even and >= 4.
// ---------------------------------------------------------------------------
template<int CDT>
__global__ __launch_bounds__(256, 4) void gemm64(
    const u16* __restrict__ A0, const u16* __restrict__ A1, const u16* __restrict__ A2,
    const u16* __restrict__ W0, const u16* __restrict__ W1, const u16* __restrict__ W2,
    const float* __restrict__ b0, const float* __restrict__ b1, const float* __restrict__ b2,
    void* __restrict__ C0, void* __restrict__ C1, void* __restrict__ C2,
    int acts, int N, int K, int lda, int ldw, int lognyb,
    i64 zA, i64 zW, i64 zB, i64 zC, int biasAllZ)
{
  constexpr int LDT = 72;
  __shared__ __align__(16) u16 As[2][64 * LDT];
  __shared__ __align__(16) u16 Bs[2][64 * LDT];
  const int tid = threadIdx.x;
  const int by = blockIdx.y;
  const int z = blockIdx.z;
  const int seg = by >> lognyb;
  const int ny = by & ((1 << lognyb) - 1);
  const u16* A = (seg == 0 ? A0 : (seg == 1 ? A1 : A2)) + (size_t)z * zA;
  const u16* W = (seg == 0 ? W0 : (seg == 1 ? W1 : W2)) + (size_t)z * zW;
  const float* bias = (seg == 0 ? b0 : (seg == 1 ? b1 : b2)) + (size_t)z * zB;
  void* Cv = seg == 0 ? C0 : (seg == 1 ? C1 : C2);
  const int act = (acts >> (2 * seg)) & 3;
  const bool dobias = biasAllZ || (z == 0);

  const int bm0 = blockIdx.x * 64, bn0 = ny * 64;
  const int lane = tid & 63, wid = tid >> 6;
  const int wr = wid >> 1, wc = wid & 1;
  const int l15 = lane & 15, lg = lane >> 4;
  const int srow = tid >> 2, scg = (tid & 3) * 16;
  const u16* Ap = A + (size_t)(bm0 + srow) * lda + scg;
  const u16* Wp = W + (size_t)(bn0 + srow) * ldw + scg;
  const int nk = K >> 6;

  uint4 a00, a01, b00, b01;   // set 0
  uint4 a10, a11, b10, b11;   // set 1
#define LDSET0(k) { a00 = *(const uint4*)(Ap + (k) * 64); a01 = *(const uint4*)(Ap + (k) * 64 + 8); \
                    b00 = *(const uint4*)(Wp + (k) * 64); b01 = *(const uint4*)(Wp + (k) * 64 + 8); }
#define LDSET1(k) { a10 = *(const uint4*)(Ap + (k) * 64); a11 = *(const uint4*)(Ap + (k) * 64 + 8); \
                    b10 = *(const uint4*)(Wp + (k) * 64); b11 = *(const uint4*)(Wp + (k) * 64 + 8); }
#define STSET0(buf) { *(uint4*)&As[buf][srow * LDT + scg] = a00; *(uint4*)&As[buf][srow * LDT + scg + 8] = a01; \
                      *(uint4*)&Bs[buf][srow * LDT + scg] = b00; *(uint4*)&Bs[buf][srow * LDT + scg + 8] = b01; }
#define STSET1(buf) { *(uint4*)&As[buf][srow * LDT + scg] = a10; *(uint4*)&As[buf][srow * LDT + scg + 8] = a11; \
                      *(uint4*)&Bs[buf][srow * LDT + scg] = b10; *(uint4*)&Bs[buf][srow * LDT + scg + 8] = b11; }

  f32x4v acc[2][2] = {};
  auto mfma_on = [&](int buf) {
    bf16x8 af[2][2], bw[2][2];
#pragma unroll
    for (int kk = 0; kk < 2; ++kk) {
#pragma unroll
      for (int mm = 0; mm < 2; ++mm)
        af[kk][mm] = *(const bf16x8*)&As[buf][(wr * 32 + mm * 16 + l15) * LDT + kk * 32 + lg * 8];
#pragma unroll
      for (int nn = 0; nn < 2; ++nn)
        bw[kk][nn] = *(const bf16x8*)&Bs[buf][(wc * 32 + nn * 16 + l15) * LDT + kk * 32 + lg * 8];
    }
#pragma unroll
    for (int kk = 0; kk < 2; ++kk)
#pragma unroll
      for (int mm = 0; mm < 2; ++mm)
#pragma unroll
        for (int nn = 0; nn < 2; ++nn)
          acc[mm][nn] = __builtin_amdgcn_mfma_f32_16x16x32_bf16(af[kk][mm], bw[kk][nn], acc[mm][nn], 0, 0, 0);
  };

  // prologue: T0 -> LDS0, T1 -> regs(set1)
  LDSET0(0); STSET0(0);
  LDSET1(1);
  __syncthreads();
  for (int k = 0; k < nk; k += 2) {
    if (k + 2 < nk) LDSET0(k + 2);
    mfma_on(0);
    STSET1(1);                  // tile k+1 -> LDS1
    __syncthreads();
    if (k + 3 < nk) LDSET1(k + 3);
    mfma_on(1);
    if (k + 2 < nk) STSET0(0);  // tile k+2 -> LDS0
    __syncthreads();
  }
#undef LDSET0
#undef LDSET1
#undef STSET0
#undef STSET1
#pragma unroll
  for (int nn = 0; nn < 2; ++nn) {
    const int col = bn0 + wc * 32 + nn * 16 + l15;
    const float bv = dobias ? bias[col] : 0.f;
#pragma unroll
    for (int mm = 0; mm < 2; ++mm) {
#pragma unroll
      for (int r = 0; r < 4; ++r) {
        const int row = bm0 + wr * 32 + mm * 16 + lg * 4 + r;
        float v = acc[mm][nn][r] + bv;
        if (act == 1) v = v > 0.f ? v + 1.f : __expf(v);
        else if (act == 2) v = 0.5f * v * (1.f + erff(v * 0.70710678f));
        const size_t idx = (size_t)row * N + col + (size_t)z * zC;
        if (CDT == 0) ((float*)Cv)[idx] = v;
        else          ((u16*)Cv)[idx] = f2bf(v);
      }
    }
  }
}

// ---------------------------------------------------------------------------
// Chunk sums (MFMA), z-batched over layers: KVt[m][d] = sum_s V[s][m]*K[s][d],
// z[d] = sum_s K[s][d].  Inputs bf16.
// ---------------------------------------------------------------------------
__global__ __launch_bounds__(256) void lin_chunk_mfma(
    const u16* __restrict__ kbuf, const u16* __restrict__ vbuf,
    float* __restrict__ KVc, float* __restrict__ zc)
{
  constexpr int LDT = 72;
  __shared__ __align__(16) u16 Kt[64 * LDT];   // Kt[d][s]
  __shared__ __align__(16) u16 Vt[64 * LDT];   // Vt[m][s]
  const int c = blockIdx.x, bh = blockIdx.y, zl = blockIdx.z;
  kbuf += (size_t)zl * 2048 * 512;
  vbuf += (size_t)zl * 2048 * 512;
  KVc  += (size_t)zl * 16 * 16 * 4096;
  zc   += (size_t)zl * 16 * 16 * 64;
  const int b = bh >> 3, h = bh & 7;
  const int t = threadIdx.x;
  const size_t rowbase = (size_t)(b * 1024 + c * 64);
  const int sp = t >> 4, colq = (t & 15) * 4;
#pragma unroll
  for (int pp = 0; pp < 2; ++pp) {
    const int s0 = pp * 32 + 2 * sp;
    const ushort4 ka = *(const ushort4*)&kbuf[(rowbase + s0) * 512 + h * 64 + colq];
    const ushort4 kb_ = *(const ushort4*)&kbuf[(rowbase + s0 + 1) * 512 + h * 64 + colq];
    const ushort4 va = *(const ushort4*)&vbuf[(rowbase + s0) * 512 + h * 64 + colq];
    const ushort4 vb_ = *(const ushort4*)&vbuf[(rowbase + s0 + 1) * 512 + h * 64 + colq];
    *(unsigned*)&Kt[(colq + 0) * LDT + s0] = (unsigned)ka.x | ((unsigned)kb_.x << 16);
    *(unsigned*)&Kt[(colq + 1) * LDT + s0] = (unsigned)ka.y | ((unsigned)kb_.y << 16);
    *(unsigned*)&Kt[(colq + 2) * LDT + s0] = (unsigned)ka.z | ((unsigned)kb_.z << 16);
    *(unsigned*)&Kt[(colq + 3) * LDT + s0] = (unsigned)ka.w | ((unsigned)kb_.w << 16);
    *(unsigned*)&Vt[(colq + 0) * LDT + s0] = (unsigned)va.x | ((unsigned)vb_.x << 16);
    *(unsigned*)&Vt[(colq + 1) * LDT + s0] = (unsigned)va.y | ((unsigned)vb_.y << 16);
    *(unsigned*)&Vt[(colq + 2) * LDT + s0] = (unsigned)va.z | ((unsigned)vb_.z << 16);
    *(unsigned*)&Vt[(colq + 3) * LDT + s0] = (unsigned)va.w | ((unsigned)vb_.w << 16);
  }
  __syncthreads();
  {
    const int zd = t >> 2, zg = t & 3;
    float zp = 0.f;
#pragma unroll
    for (int ss = 0; ss < 16; ++ss) zp += bf2f(Kt[zd * LDT + zg * 16 + ss]);
    zp += __shfl_xor(zp, 1, 64);
    zp += __shfl_xor(zp, 2, 64);
    if (zg == 0) zc[(size_t)(bh * 16 + c) * 64 + zd] = zp;
  }
  const int lane = t & 63, wid = t >> 6;
  const int wr = wid >> 1, wc = wid & 1;
  const int l15 = lane & 15, lg = lane >> 4;
  bf16x8 av[2][2], bk[2][2];
#pragma unroll
  for (int kk = 0; kk < 2; ++kk) {
#pragma unroll
    for (int mm = 0; mm < 2; ++mm)
      av[kk][mm] = *(const bf16x8*)&Vt[(wr * 32 + mm * 16 + l15) * LDT + kk * 32 + lg * 8];
#pragma unroll
    for (int nn = 0; nn < 2; ++nn)
      bk[kk][nn] = *(const bf16x8*)&Kt[(wc * 32 + nn * 16 + l15) * LDT + kk * 32 + lg * 8];
  }
  f32x4v acc[2][2] = {};
#pragma unroll
  for (int kk = 0; kk < 2; ++kk)
#pragma unroll
    for (int mm = 0; mm < 2; ++mm)
#pragma unroll
      for (int nn = 0; nn < 2; ++nn)
        acc[mm][nn] = __builtin_amdgcn_mfma_f32_16x16x32_bf16(av[kk][mm], bk[kk][nn], acc[mm][nn], 0, 0, 0);
  float* kvout = KVc + (size_t)(bh * 16 + c) * 4096;
#pragma unroll
  for (int mm = 0; mm < 2; ++mm)
#pragma unroll
    for (int r = 0; r < 4; ++r) {
      const int row = wr * 32 + mm * 16 + lg * 4 + r;
#pragma unroll
      for (int nn = 0; nn < 2; ++nn) {
        const int col = wc * 32 + nn * 16 + l15;
        kvout[row * 64 + col] = acc[mm][nn][r];
      }
    }
}

// ---------------------------------------------------------------------------
// SA apply (MFMA): prefix-sums KVc/zc chunks [0,c) in-kernel, then
// S=Q@K^T masked; O = S@V + Q@KVprefix; den = rowsum(S)+Q.zp.  bf16 in/out.
// ---------------------------------------------------------------------------
__global__ __launch_bounds__(256) void sa_apply_mfma(
    const u16* __restrict__ qbuf, const u16* __restrict__ kbuf,
    const u16* __restrict__ vbuf, const float* __restrict__ KVc,
    const float* __restrict__ zc, u16* __restrict__ out)
{
  constexpr int LDT = 72;
  __shared__ __align__(16) u16 Qs[64 * LDT];
  __shared__ __align__(16) u16 Ks[64 * LDT];
  __shared__ __align__(16) u16 Vt[64 * LDT];
  __shared__ __align__(16) u16 Ps[64 * LDT];
  __shared__ __align__(16) u16 KVs[64 * LDT];
  __shared__ float zp[64];
  __shared__ float den1[2][64];
  __shared__ float den2[64];
  const int c = blockIdx.x, bh = blockIdx.y;
  const int b = bh >> 3, h = bh & 7;
  const int t = threadIdx.x;
  const size_t rowbase = (size_t)(b * 1024 + c * 64);
  {
    const int srow = t >> 2, scg = (t & 3) * 16;
    *(uint4*)&Qs[srow * LDT + scg]     = *(const uint4*)&qbuf[(rowbase + srow) * 512 + h * 64 + scg];
    *(uint4*)&Qs[srow * LDT + scg + 8] = *(const uint4*)&qbuf[(rowbase + srow) * 512 + h * 64 + scg + 8];
    *(uint4*)&Ks[srow * LDT + scg]     = *(const uint4*)&kbuf[(rowbase + srow) * 512 + h * 64 + scg];
    *(uint4*)&Ks[srow * LDT + scg + 8] = *(const uint4*)&kbuf[(rowbase + srow) * 512 + h * 64 + scg + 8];
    const float* kvbase = KVc + (size_t)(bh * 16) * 4096 + srow * 64 + scg;
    float4 s0 = make_float4(0, 0, 0, 0), s1 = s0, s2 = s0, s3 = s0;
    for (int cc = 0; cc < c; ++cc) {
      const float* p = kvbase + (size_t)cc * 4096;
      const float4 a0 = *(const float4*)&p[0];
      const float4 a1 = *(const float4*)&p[4];
      const float4 a2 = *(const float4*)&p[8];
      const float4 a3 = *(const float4*)&p[12];
      s0.x += a0.x; s0.y += a0.y; s0.z += a0.z; s0.w += a0.w;
      s1.x += a1.x; s1.y += a1.y; s1.z += a1.z; s1.w += a1.w;
      s2.x += a2.x; s2.y += a2.y; s2.z += a2.z; s2.w += a2.w;
      s3.x += a3.x; s3.y += a3.y; s3.z += a3.z; s3.w += a3.w;
    }
    *(ushort4*)&KVs[srow * LDT + scg + 0]  = make_ushort4(f2bf(s0.x), f2bf(s0.y), f2bf(s0.z), f2bf(s0.w));
    *(ushort4*)&KVs[srow * LDT + scg + 4]  = make_ushort4(f2bf(s1.x), f2bf(s1.y), f2bf(s1.z), f2bf(s1.w));
    *(ushort4*)&KVs[srow * LDT + scg + 8]  = make_ushort4(f2bf(s2.x), f2bf(s2.y), f2bf(s2.z), f2bf(s2.w));
    *(ushort4*)&KVs[srow * LDT + scg + 12] = make_ushort4(f2bf(s3.x), f2bf(s3.y), f2bf(s3.z), f2bf(s3.w));
  }
  {
    const int sp = t >> 4, colq = (t & 15) * 4;
#pragma unroll
    for (int pp = 0; pp < 2; ++pp) {
      const int s0 = pp * 32 + 2 * sp;
      const ushort4 va = *(const ushort4*)&vbuf[(rowbase + s0) * 512 + h * 64 + colq];
      const ushort4 vb_ = *(const ushort4*)&vbuf[(rowbase + s0 + 1) * 512 + h * 64 + colq];
      *(unsigned*)&Vt[(colq + 0) * LDT + s0] = (unsigned)va.x | ((unsigned)vb_.x << 16);
      *(unsigned*)&Vt[(colq + 1) * LDT + s0] = (unsigned)va.y | ((unsigned)vb_.y << 16);
      *(unsigned*)&Vt[(colq + 2) * LDT + s0] = (unsigned)va.z | ((unsigned)vb_.z << 16);
      *(unsigned*)&Vt[(colq + 3) * LDT + s0] = (unsigned)va.w | ((unsigned)vb_.w << 16);
    }
  }
  if (t < 64) {
    float z = 0.f;
    for (int cc = 0; cc < c; ++cc) z += zc[(size_t)(bh * 16 + cc) * 64 + t];
    zp[t] = z;
  }
  __syncthreads();
  {
    const int di = t >> 2, dg = t & 3;
    float p2 = 0.f;
#pragma unroll
    for (int dd = 0; dd < 16; ++dd)
      p2 += bf2f(Qs[di * LDT + dg * 16 + dd]) * zp[dg * 16 + dd];
    p2 += __shfl_xor(p2, 1, 64);
    p2 += __shfl_xor(p2, 2, 64);
    if (dg == 0) den2[di] = p2;
  }
  const int lane = t & 63, wid = t >> 6;
  const int wr = wid >> 1, wc = wid & 1;
  const int l15 = lane & 15, lg = lane >> 4;
  bf16x8 af_q[2][2], bx[2][2];
#pragma unroll
  for (int kk = 0; kk < 2; ++kk) {
#pragma unroll
    for (int mm = 0; mm < 2; ++mm)
      af_q[kk][mm] = *(const bf16x8*)&Qs[(wr * 32 + mm * 16 + l15) * LDT + kk * 32 + lg * 8];
#pragma unroll
    for (int nn = 0; nn < 2; ++nn)
      bx[kk][nn] = *(const bf16x8*)&Ks[(wc * 32 + nn * 16 + l15) * LDT + kk * 32 + lg * 8];
  }
  f32x4v s_acc[2][2] = {};
#pragma unroll
  for (int kk = 0; kk < 2; ++kk)
#pragma unroll
    for (int mm = 0; mm < 2; ++mm)
#pragma unroll
      for (int nn = 0; nn < 2; ++nn)
        s_acc[mm][nn] = __builtin_amdgcn_mfma_f32_16x16x32_bf16(af_q[kk][mm], bx[kk][nn], s_acc[mm][nn], 0, 0, 0);
#pragma unroll
  for (int mm = 0; mm < 2; ++mm)
#pragma unroll
    for (int r = 0; r < 4; ++r) {
      const int row = wr * 32 + mm * 16 + lg * 4 + r;
      float dsum = 0.f;
#pragma unroll
      for (int nn = 0; nn < 2; ++nn) {
        const int col = wc * 32 + nn * 16 + l15;
        const float val = (col <= row) ? s_acc[mm][nn][r] : 0.f;
        Ps[row * LDT + col] = f2bf(val);
        dsum += val;
      }
      dsum += __shfl_xor(dsum, 1, 64);
      dsum += __shfl_xor(dsum, 2, 64);
      dsum += __shfl_xor(dsum, 4, 64);
      dsum += __shfl_xor(dsum, 8, 64);
      if (l15 == 0) den1[wc][row] = dsum;
    }
  __syncthreads();
  bf16x8 ap[2][2];
#pragma unroll
  for (int kk = 0; kk < 2; ++kk) {
#pragma unroll
    for (int mm = 0; mm < 2; ++mm)
      ap[kk][mm] = *(const bf16x8*)&Ps[(wr * 32 + mm * 16 + l15) * LDT + kk * 32 + lg * 8];
#pragma unroll
    for (int nn = 0; nn < 2; ++nn)
      bx[kk][nn] = *(const bf16x8*)&Vt[(wc * 32 + nn * 16 + l15) * LDT + kk * 32 + lg * 8];
  }
  f32x4v o_acc[2][2] = {};
#pragma unroll
  for (int kk = 0; kk < 2; ++kk)
#pragma unroll
    for (int mm = 0; mm < 2; ++mm)
#pragma unroll
      for (int nn = 0; nn < 2; ++nn)
        o_acc[mm][nn] = __builtin_amdgcn_mfma_f32_16x16x32_bf16(ap[kk][mm], bx[kk][nn], o_acc[mm][nn], 0, 0, 0);
#pragma unroll
  for (int kk = 0; kk < 2; ++kk)
#pragma unroll
    for (int nn = 0; nn < 2; ++nn)
      bx[kk][nn] = *(const bf16x8*)&KVs[(wc * 32 + nn * 16 + l15) * LDT + kk * 32 + lg * 8];
#pragma unroll
  for (int kk = 0; kk < 2; ++kk)
#pragma unroll
    for (int mm = 0; mm < 2; ++mm)
#pragma unroll
      for (int nn = 0; nn < 2; ++nn)
        o_acc[mm][nn] = __builtin_amdgcn_mfma_f32_16x16x32_bf16(af_q[kk][mm], bx[kk][nn], o_acc[mm][nn], 0, 0, 0);
#pragma unroll
  for (int mm = 0; mm < 2; ++mm)
#pragma unroll
    for (int r = 0; r < 4; ++r) {
      const int row = wr * 32 + mm * 16 + lg * 4 + r;
      const float rden = 1.f / (den1[0][row] + den1[1][row] + den2[row] + 1e-6f);
#pragma unroll
      for (int nn = 0; nn < 2; ++nn) {
        const int col = wc * 32 + nn * 16 + l15;
        out[(rowbase + row) * 512 + h * 64 + col] = f2bf(o_acc[mm][nn][r] * rden);
      }
    }
}

// ---------------------------------------------------------------------------
// CA apply (MFMA): q = phi(sum of 2 f32 split-K partials); KVtot summed
// in-kernel; O = Q@KVtot / (Q.ztot + eps).
// ---------------------------------------------------------------------------
__global__ __launch_bounds__(256) void ca_apply_mfma(
    const float* __restrict__ qp0, i64 qstride, const float* __restrict__ KVc,
    const float* __restrict__ zc, u16* __restrict__ out)
{
  constexpr int LDT = 72;
  __shared__ __align__(16) u16 Qs[64 * LDT];
  __shared__ __align__(16) u16 KVs[64 * LDT];
  __shared__ float zt[64];
  __shared__ float den2[64];
  const int c = blockIdx.x, bh = blockIdx.y;
  const int b = bh >> 3, h = bh & 7;
  const int t = threadIdx.x;
  const size_t rowbase = (size_t)(b * 1024 + c * 64);
  {
    const int srow = t >> 2, scg = (t & 3) * 16;
    const float* qa = qp0 + (rowbase + srow) * 512 + h * 64 + scg;
    const float* qb = qa + qstride;
#pragma unroll
    for (int i = 0; i < 4; ++i) {
      const float4 u = *(const float4*)&qa[i * 4];
      const float4 w = *(const float4*)&qb[i * 4];
      float e0 = u.x + w.x, e1 = u.y + w.y, e2 = u.z + w.z, e3 = u.w + w.w;
      e0 = e0 > 0.f ? e0 + 1.f : __expf(e0);
      e1 = e1 > 0.f ? e1 + 1.f : __expf(e1);
      e2 = e2 > 0.f ? e2 + 1.f : __expf(e2);
      e3 = e3 > 0.f ? e3 + 1.f : __expf(e3);
      *(ushort4*)&Qs[srow * LDT + scg + i * 4] = make_ushort4(f2bf(e0), f2bf(e1), f2bf(e2), f2bf(e3));
    }
    const float* kvbase = KVc + (size_t)(bh * 16) * 4096 + srow * 64 + scg;
    float4 s0 = make_float4(0, 0, 0, 0), s1 = s0, s2 = s0, s3 = s0;
    for (int cc = 0; cc < 16; ++cc) {
      const float* p = kvbase + (size_t)cc * 4096;
      const float4 a0 = *(const float4*)&p[0];
      const float4 a1 = *(const float4*)&p[4];
      const float4 a2 = *(const float4*)&p[8];
      const float4 a3 = *(const float4*)&p[12];
      s0.x += a0.x; s0.y += a0.y; s0.z += a0.z; s0.w += a0.w;
      s1.x += a1.x; s1.y += a1.y; s1.z += a1.z; s1.w += a1.w;
      s2.x += a2.x; s2.y += a2.y; s2.z += a2.z; s2.w += a2.w;
      s3.x += a3.x; s3.y += a3.y; s3.z += a3.z; s3.w += a3.w;
    }
    *(ushort4*)&KVs[srow * LDT + scg + 0]  = make_ushort4(f2bf(s0.x), f2bf(s0.y), f2bf(s0.z), f2bf(s0.w));
    *(ushort4*)&KVs[srow * LDT + scg + 4]  = make_ushort4(f2bf(s1.x), f2bf(s1.y), f2bf(s1.z), f2bf(s1.w));
    *(ushort4*)&KVs[srow * LDT + scg + 8]  = make_ushort4(f2bf(s2.x), f2bf(s2.y), f2bf(s2.z), f2bf(s2.w));
    *(ushort4*)&KVs[srow * LDT + scg + 12] = make_ushort4(f2bf(s3.x), f2bf(s3.y), f2bf(s3.z), f2bf(s3.w));
  }
  if (t < 64) {
    float z = 0.f;
    for (int cc = 0; cc < 16; ++cc) z += zc[(size_t)(bh * 16 + cc) * 64 + t];
    zt[t] = z;
  }
  __syncthreads();
  {
    const int di = t >> 2, dg = t & 3;
    float p2 = 0.f;
#pragma unroll
    for (int dd = 0; dd < 16; ++dd)
      p2 += bf2f(Qs[di * LDT + dg * 16 + dd]) * zt[dg * 16 + dd];
    p2 += __shfl_xor(p2, 1, 64);
    p2 += __shfl_xor(p2, 2, 64);
    if (dg == 0) den2[di] = p2;
  }
  const int lane = t & 63, wid = t >> 6;
  const int wr = wid >> 1, wc = wid & 1;
  const int l15 = lane & 15, lg = lane >> 4;
  bf16x8 aq[2][2], bkv[2][2];
#pragma unroll
  for (int kk = 0; kk < 2; ++kk) {
#pragma unroll
    for (int mm = 0; mm < 2; ++mm)
      aq[kk][mm] = *(const bf16x8*)&Qs[(wr * 32 + mm * 16 + l15) * LDT + kk * 32 + lg * 8];
#pragma unroll
    for (int nn = 0; nn < 2; ++nn)
      bkv[kk][nn] = *(const bf16x8*)&KVs[(wc * 32 + nn * 16 + l15) * LDT + kk * 32 + lg * 8];
  }
  f32x4v o_acc[2][2] = {};
#pragma unroll
  for (int kk = 0; kk < 2; ++kk)
#pragma unroll
    for (int mm = 0; mm < 2; ++mm)
#pragma unroll
      for (int nn = 0; nn < 2; ++nn)
        o_acc[mm][nn] = __builtin_amdgcn_mfma_f32_16x16x32_bf16(aq[kk][mm], bkv[kk][nn], o_acc[mm][nn], 0, 0, 0);
  __syncthreads();
#pragma unroll
  for (int mm = 0; mm < 2; ++mm)
#pragma unroll
    for (int r = 0; r < 4; ++r) {
      const int row = wr * 32 + mm * 16 + lg * 4 + r;
      const float rden = 1.f / (den2[row] + 1e-6f);
#pragma unroll
      for (int nn = 0; nn < 2; ++nn) {
        const int col = wc * 32 + nn * 16 + l15;
        out[(rowbase + row) * 512 + h * 64 + col] = f2bf(o_acc[mm][nn][r] * rden);
      }
    }
}

// ---------------------------------------------------------------------------
// LayerNorm: x = LN(x + sum_p a_p) in place (f32) + bf16 mirror xb.
// ---------------------------------------------------------------------------
template<int NPART>
__global__ __launch_bounds__(256) void ln_residual(
    float* __restrict__ x, const float* __restrict__ a, i64 pstride,
    const float* __restrict__ g, const float* __restrict__ bt,
    u16* __restrict__ xb)
{
  const int t = threadIdx.x, lane = t & 63, w = t >> 6;
  const int row = blockIdx.x * 4 + w;
  float* xr = x + (size_t)row * 512;
  float4 x0 = *(const float4*)&xr[lane * 8];
  float4 x1 = *(const float4*)&xr[lane * 8 + 4];
  float v[8] = { x0.x, x0.y, x0.z, x0.w, x1.x, x1.y, x1.z, x1.w };
#pragma unroll
  for (int p = 0; p < NPART; ++p) {
    const float* ar = a + (size_t)p * pstride + (size_t)row * 512;
    float4 a0 = *(const float4*)&ar[lane * 8];
    float4 a1 = *(const float4*)&ar[lane * 8 + 4];
    v[0] += a0.x; v[1] += a0.y; v[2] += a0.z; v[3] += a0.w;
    v[4] += a1.x; v[5] += a1.y; v[6] += a1.z; v[7] += a1.w;
  }
  float s = 0.f, sq = 0.f;
#pragma unroll
  for (int i = 0; i < 8; ++i) { s += v[i]; sq += v[i] * v[i]; }
#pragma unroll
  for (int off = 32; off > 0; off >>= 1) {
    s += __shfl_xor(s, off, 64);
    sq += __shfl_xor(sq, off, 64);
  }
  const float mean = s * (1.f / 512.f);
  const float var = sq * (1.f / 512.f) - mean * mean;
  const float rstd = rsqrtf(var + 1e-5f);
  float o[8];
#pragma unroll
  for (int i = 0; i < 8; ++i) {
    const int col = lane * 8 + i;
    o[i] = (v[i] - mean) * rstd * g[col] + bt[col];
  }
  *(float4*)&xr[lane * 8]     = make_float4(o[0], o[1], o[2], o[3]);
  *(float4*)&xr[lane * 8 + 4] = make_float4(o[4], o[5], o[6], o[7]);
  *(ushort4*)&xb[(size_t)row * 512 + lane * 8]     = make_ushort4(f2bf(o[0]), f2bf(o[1]), f2bf(o[2]), f2bf(o[3]));
  *(ushort4*)&xb[(size_t)row * 512 + lane * 8 + 4] = make_ushort4(f2bf(o[4]), f2bf(o[5]), f2bf(o[6]), f2bf(o[7]));
}

__global__ __launch_bounds__(256) void ln_final(
    const float* __restrict__ x, const float* __restrict__ g,
    const float* __restrict__ bt, float* __restrict__ out)
{
  const int t = threadIdx.x, lane = t & 63, w = t >> 6;
  const int row = blockIdx.x * 4 + w;
  const float* xr = x + (size_t)row * 512;
  float4 x0 = *(const float4*)&xr[lane * 8];
  float4 x1 = *(const float4*)&xr[lane * 8 + 4];
  float v[8] = { x0.x, x0.y, x0.z, x0.w, x1.x, x1.y, x1.z, x1.w };
  float s = 0.f, sq = 0.f;
#pragma unroll
  for (int i = 0; i < 8; ++i) { s += v[i]; sq += v[i] * v[i]; }
#pragma unroll
  for (int off = 32; off > 0; off >>= 1) {
    s += __shfl_xor(s, off, 64);
    sq += __shfl_xor(sq, off, 64);
  }
  const float mean = s * (1.f / 512.f);
  const float var = sq * (1.f / 512.f) - mean * mean;
  const float rstd = rsqrtf(var + 1e-5f);
  float o[8];
#pragma unroll
  for (int i = 0; i < 8; ++i) {
    const int col = lane * 8 + i;
    o[i] = (v[i] - mean) * rstd * g[col] + bt[col];
  }
  *(float4*)&out[(size_t)row * 512 + lane * 8]     = make_float4(o[0], o[1], o[2], o[3]);
  *(float4*)&out[(size_t)row * 512 + lane * 8 + 4] = make_float4(o[4], o[5], o[6], o[7]);
}

// ---------------------------------------------------------------------------
extern "C" void kernel_launch(void* const* d_in, const int* in_sizes, int n_in,
                              void* d_out, int out_size, void* d_ws, size_t ws_size,
                              hipStream_t stream)
{
  (void)in_sizes; (void)n_in; (void)out_size; (void)ws_size;
  constexpr int Dm = 512, Lc = 4, FFc = 2048;
  constexpr i64 TOK = 2048LL * 512;

  const float* memory = (const float*)d_in[0];
  const float* target = (const float*)d_in[1];
  const float *saW[4], *sab[4], *caW[4], *cab[4];
  for (int j = 0; j < 4; ++j) {
    saW[j] = (const float*)d_in[2 + 2 * j];
    sab[j] = (const float*)d_in[3 + 2 * j];
    caW[j] = (const float*)d_in[10 + 2 * j];
    cab[j] = (const float*)d_in[11 + 2 * j];
  }
  const float* ffW1 = (const float*)d_in[18];
  const float* ffb1 = (const float*)d_in[19];
  const float* ffW2 = (const float*)d_in[20];
  const float* ffb2 = (const float*)d_in[21];
  const float* lng[4] = { (const float*)d_in[22], (const float*)d_in[24],
                          (const float*)d_in[26], (const float*)d_in[28] };
  const float* lnb[4] = { (const float*)d_in[23], (const float*)d_in[25],
                          (const float*)d_in[27], (const float*)d_in[29] };

  size_t off = 0;
  auto alloc = [&](size_t bytes) -> void* {
    void* p = (char*)d_ws + off;
    off += (bytes + 255) & ~(size_t)255;
    return p;
  };
  u16* WtS[4]; u16* WtC[4];
  for (int j = 0; j < 4; ++j) WtS[j] = (u16*)alloc((size_t)Lc * Dm * Dm * 2);
  for (int j = 0; j < 4; ++j) WtC[j] = (u16*)alloc((size_t)Lc * Dm * Dm * 2);
  u16* WtF1 = (u16*)alloc((size_t)Lc * Dm * FFc * 2);
  u16* WtF2 = (u16*)alloc((size_t)Lc * FFc * Dm * 2);
  float* x     = (float*)alloc(TOK * 4);
  u16*   xb    = (u16*)alloc(TOK * 2);
  u16*   memb  = (u16*)alloc(TOK * 2);
  u16*   qh    = (u16*)alloc(TOK * 2);
  u16*   kh    = (u16*)alloc(TOK * 2);
  u16*   vh    = (u16*)alloc(TOK * 2);
  u16*   khAll = (u16*)alloc((size_t)Lc * TOK * 2);
  u16*   vhAll = (u16*)alloc((size_t)Lc * TOK * 2);
  float* resid = (float*)alloc((size_t)4 * TOK * 4);      // up to 4 split-K partials
  u16*   attn  = (u16*)alloc(TOK * 2);
  u16*   ffh   = (u16*)alloc((size_t)2048 * 2048 * 2);
  float* KVc   = (float*)alloc((size_t)16 * 16 * 4096 * 4);
  float* zcb   = (float*)alloc((size_t)16 * 16 * 64 * 4);
  float* KVcA  = (float*)alloc((size_t)Lc * 16 * 16 * 4096 * 4);
  float* zcbA  = (float*)alloc((size_t)Lc * 16 * 16 * 64 * 4);

  {
    P8i pin; P8o pout;
    for (int j = 0; j < 4; ++j) { pin.p[j] = saW[j]; pout.p[j] = WtS[j]; }
    for (int j = 0; j < 4; ++j) { pin.p[4 + j] = caW[j]; pout.p[4 + j] = WtC[j]; }
    transpose_b8<<<dim3(8, 8, 32), 256, 0, stream>>>(pin, pout);
  }
  transpose_f2b<<<dim3(32, 8, 4), 256, 0, stream>>>(ffW1, WtF1, Dm, FFc);
  transpose_f2b<<<dim3(8, 32, 4), 256, 0, stream>>>(ffW2, WtF2, FFc, Dm);

  cast_dual<<<512, 256, 0, stream>>>(target, x, xb);
  cast_dual<<<512, 256, 0, stream>>>(memory, nullptr, memb);

  // ---- hoisted: CA K/V projections for ALL layers (2048 blocks) ----
  gemm64<1><<<dim3(32, 16, 4), 256, 0, stream>>>(
      memb, memb, memb, WtC[1], WtC[2], WtC[2],
      cab[1], cab[2], cab[2], khAll, vhAll, vhAll,
      0x01, 512, 512, 512, 512, 3,
      0, (i64)Dm * Dm, (i64)Dm, TOK, 1);
  lin_chunk_mfma<<<dim3(16, 16, 4), 256, 0, stream>>>(khAll, vhAll, KVcA, zcbA);

  for (int i = 0; i < Lc; ++i) {
    const size_t wo  = (size_t)i * Dm * Dm;
    const size_t wo1 = (size_t)i * Dm * FFc;
    const size_t wo2 = (size_t)i * FFc * Dm;
    // ---- causal linear self-attention ----
    gemm64<1><<<dim3(32, 24), 256, 0, stream>>>(
        xb, xb, xb, WtS[0] + wo, WtS[1] + wo, WtS[2] + wo,
        sab[0] + i * Dm, sab[1] + i * Dm, sab[2] + i * Dm,
        qh, kh, vh, 0x05, 512, 512, 512, 512, 3, 0, 0, 0, 0, 1);
    lin_chunk_mfma<<<dim3(16, 16), 256, 0, stream>>>(kh, vh, KVc, zcb);
    sa_apply_mfma<<<dim3(16, 16), 256, 0, stream>>>(qh, kh, vh, KVc, zcb, attn);
    gemm64<0><<<dim3(32, 8, 2), 256, 0, stream>>>(       // Wo(SA) split-K2
        attn, attn, attn, WtS[3] + wo, WtS[3] + wo, WtS[3] + wo,
        sab[3] + i * Dm, sab[3] + i * Dm, sab[3] + i * Dm,
        resid, resid, resid, 0, 512, 256, 512, 512, 3,
        256, 256, 0, TOK, 0);
    ln_residual<2><<<512, 256, 0, stream>>>(x, resid, TOK, lng[0] + i * Dm, lnb[0] + i * Dm, xb);
    // ---- linear cross-attention (K/V + chunks precomputed) ----
    gemm64<0><<<dim3(32, 8, 2), 256, 0, stream>>>(       // CA Q split-K2 (no act)
        xb, xb, xb, WtC[0] + wo, WtC[0] + wo, WtC[0] + wo,
        cab[0] + i * Dm, cab[0] + i * Dm, cab[0] + i * Dm,
        resid, resid, resid, 0, 512, 256, 512, 512, 3,
        256, 256, 0, TOK, 0);
    ca_apply_mfma<<<dim3(16, 16), 256, 0, stream>>>(
        resid, TOK, KVcA + (size_t)i * 16 * 16 * 4096, zcbA + (size_t)i * 16 * 16 * 64, attn);
    gemm64<0><<<dim3(32, 8, 2), 256, 0, stream>>>(       // Wo(CA) split-K2
        attn, attn, attn, WtC[3] + wo, WtC[3] + wo, WtC[3] + wo,
        cab[3] + i * Dm, cab[3] + i * Dm, cab[3] + i * Dm,
        resid, resid, resid, 0, 512, 256, 512, 512, 3,
        256, 256, 0, TOK, 0);
    ln_residual<2><<<512, 256, 0, stream>>>(x, resid, TOK, lng[1] + i * Dm, lnb[1] + i * Dm, xb);
    // ---- FFN (FFN2 split-K4) ----
    gemm64<1><<<dim3(32, 32), 256, 0, stream>>>(
        xb, xb, xb, WtF1 + wo1, WtF1 + wo1, WtF1 + wo1,
        ffb1 + i * FFc, ffb1 + i * FFc, ffb1 + i * FFc,
        ffh, ffh, ffh, 2, 2048, 512, 512, 512, 5, 0, 0, 0, 0, 1);
    gemm64<0><<<dim3(32, 8, 4), 256, 0, stream>>>(
        ffh, ffh, ffh, WtF2 + wo2, WtF2 + wo2, WtF2 + wo2,
        ffb2 + i * Dm, ffb2 + i * Dm, ffb2 + i * Dm,
        resid, resid, resid, 0, 512, 512, 2048, 2048, 3,
        512, 512, 0, TOK, 0);
    ln_residual<4><<<512, 256, 0, stream>>>(x, resid, TOK, lng[2] + i * Dm, lnb[2] + i * Dm, xb);
  }
  ln_final<<<512, 256, 0, stream>>>(x, lng[3], lnb[3], (float*)d_out);
}